// Round 9
// baseline (1253.225 us; speedup 1.0000x reference)
//
#include <hip/hip_runtime.h>

#define N_NODES 100000
#define N_EDGES 3200000
#define N_GRAPHS 1024
#define HID 32
#define BN_EPS 1e-5f
#define NB 256

#define NBKT 512
#define NPB 196                 // nodes per bucket; NBKT*NPB = 100352 >= N_NODES
#define PART_TILE 4096
#define PART_THREADS 256
#define PART_EPT (PART_TILE / PART_THREADS)   // 16

#define ABLK 1024               // threads per aggregation block

// ---------------- helpers ----------------

__device__ __forceinline__ int lbound(const int* __restrict__ a, int n, int key) {
    int lo = 0, hi = n;
    while (lo < hi) {
        int mid = (lo + hi) >> 1;
        if (a[mid] < key) lo = mid + 1; else hi = mid;
    }
    return lo;
}

__device__ __forceinline__ float bf2f(unsigned short h) {
    return __uint_as_float((unsigned)h << 16);
}
__device__ __forceinline__ unsigned short f2bf(float x) {   // round-to-nearest-even
    unsigned u = __float_as_uint(x);
    u += 0x7fffu + ((u >> 16) & 1u);
    return (unsigned short)(u >> 16);
}

// ---------------- bucket build (multisplit only, no CSR) ----------------

__global__ void k_zero(int* __restrict__ bhist) {
    bhist[threadIdx.x] = 0;
}

__global__ void k_hist(const int* __restrict__ dst, int* __restrict__ bhist) {
    __shared__ int h[NBKT];
    for (int i = threadIdx.x; i < NBKT; i += NB) h[i] = 0;
    __syncthreads();
    for (int e = blockIdx.x * NB + threadIdx.x; e < N_EDGES; e += gridDim.x * NB)
        atomicAdd(&h[__builtin_nontemporal_load(&dst[e]) / NPB], 1);
    __syncthreads();
    for (int i = threadIdx.x; i < NBKT; i += NB)
        if (h[i]) atomicAdd(&bhist[i], h[i]);
}

__global__ void k_scan512(const int* __restrict__ bhist, int* __restrict__ bstart,
                          int* __restrict__ bcursor) {
    __shared__ int sm[NBKT];
    int t = threadIdx.x;
    int orig = bhist[t];
    sm[t] = orig;
    __syncthreads();
    for (int off = 1; off < NBKT; off <<= 1) {
        int v = (t >= off) ? sm[t - off] : 0;
        __syncthreads();
        sm[t] += v;
        __syncthreads();
    }
    int ex = sm[t] - orig;
    bstart[t] = ex;
    bcursor[t] = ex;
    if (t == NBKT - 1) bstart[NBKT] = sm[t];
}

// partition edges into bucket-major ebuf; entry = (dst_local << 17) | src  (4B)
__global__ void k_partition(const int* __restrict__ src, const int* __restrict__ dst,
                            int* __restrict__ bcursor, unsigned* __restrict__ ebuf) {
    __shared__ int lh[NBKT];
    __shared__ int lcur[NBKT];
    const int tile0 = blockIdx.x * PART_TILE;
    for (int i = threadIdx.x; i < NBKT; i += PART_THREADS) lh[i] = 0;
    __syncthreads();
    int s[PART_EPT], bk[PART_EPT], dl[PART_EPT];
#pragma unroll
    for (int k = 0; k < PART_EPT; ++k) {
        int e = tile0 + k * PART_THREADS + threadIdx.x;
        bool ok = (e < N_EDGES);
        int sv = ok ? __builtin_nontemporal_load(&src[e]) : 0;
        int dv = ok ? __builtin_nontemporal_load(&dst[e]) : 0;
        s[k] = sv;
        bk[k] = ok ? (dv / NPB) : -1;
        dl[k] = dv - bk[k] * NPB;
        if (ok) atomicAdd(&lh[bk[k]], 1);
    }
    __syncthreads();
    for (int i = threadIdx.x; i < NBKT; i += PART_THREADS)
        lcur[i] = lh[i] ? atomicAdd(&bcursor[i], lh[i]) : 0;
    __syncthreads();
#pragma unroll
    for (int k = 0; k < PART_EPT; ++k) {
        if (bk[k] >= 0) {
            int pos = atomicAdd(&lcur[bk[k]], 1);
            unsigned pk = ((unsigned)dl[k] << 17) | (unsigned)s[k];
            __builtin_nontemporal_store(pk, &ebuf[pos]);
        }
    }
}

// per-bucket degree histogram -> dinv, zs1 (no scan, no scatter)
__global__ void __launch_bounds__(ABLK) k_bdeg(const int* __restrict__ bstart,
                       const unsigned* __restrict__ ebuf, const float* __restrict__ x,
                       float* __restrict__ dinv, float* __restrict__ zs1) {
    __shared__ int hist[NPB];
    const int b = blockIdx.x;
    const int node0 = b * NPB;
    const int elo = bstart[b], ehi = bstart[b + 1];
    const int tid = threadIdx.x;
    for (int i = tid; i < NPB; i += ABLK) hist[i] = 0;
    __syncthreads();
    for (int e = elo + tid; e < ehi; e += ABLK)
        atomicAdd(&hist[ebuf[e] >> 17], 1);
    __syncthreads();
    if (tid < NPB) {
        int node = node0 + tid;
        if (node < N_NODES) {
            float di = rsqrtf((float)(hist[tid] + 1));   // +1 self-loop
            dinv[node] = di;
            zs1[node] = di * x[node];
        }
    }
}

// ---------------- layer 1: edge-centric scalar agg -> sd = (s, dinv) ----------------

__global__ void __launch_bounds__(ABLK) k_agg1(const int* __restrict__ bstart,
                       const unsigned* __restrict__ ebuf, const float* __restrict__ dinv,
                       const float* __restrict__ zs1, float2* __restrict__ sd) {
    __shared__ float acc[NPB];
    const int b = blockIdx.x;
    const int node0 = b * NPB;
    const int elo = bstart[b], ehi = bstart[b + 1];
    const int tid = threadIdx.x;
    for (int i = tid; i < NPB; i += ABLK) acc[i] = 0.0f;
    __syncthreads();
    for (int e = elo + tid; e < ehi; e += ABLK) {
        unsigned pk = ebuf[e];
        atomicAdd(&acc[pk >> 17], zs1[pk & 0x1FFFFu]);
    }
    __syncthreads();
    if (tid < NPB) {
        int node = node0 + tid;
        if (node < N_NODES) {
            float di = dinv[node];
            float s = di * (zs1[node] + acc[tid]);
            sd[node] = make_float2(s, di);
        }
    }
}

// ---------------- layer 2: edge-centric rank-1 agg + fused matmul/BN/ReLU ----------------
// zs2[u,f] = d_u*relu(s_u*A[f]+B[f]);  acc[v,f] += zs2[u,f] per edge (LDS atomic).
__global__ void __launch_bounds__(ABLK) k_agg2(const int* __restrict__ bstart,
                       const unsigned* __restrict__ ebuf, const float2* __restrict__ sd,
                       const float* __restrict__ W1, const float* __restrict__ b1,
                       const float* __restrict__ g1, const float* __restrict__ bb1,
                       const float* __restrict__ m1, const float* __restrict__ v1,
                       const float* __restrict__ W2,
                       const float* __restrict__ b2, const float* __restrict__ g2,
                       const float* __restrict__ bb2, const float* __restrict__ m2,
                       const float* __restrict__ v2,
                       unsigned short* __restrict__ zs3a,
                       unsigned short* __restrict__ zs3b) {
    __shared__ float Ws[HID * HID];
    __shared__ float As[HID], Bs[HID];
    __shared__ float acc[NPB * 33];          // padded stride 33
    const int b = blockIdx.x;
    const int node0 = b * NPB;
    const int elo = bstart[b], ehi = bstart[b + 1];
    const int tid = threadIdx.x;

    for (int k = tid; k < HID * HID; k += ABLK) Ws[k] = W2[k];
    if (tid < HID) {
        float sc1 = g1[tid] * rsqrtf(v1[tid] + BN_EPS);
        As[tid] = W1[tid] * sc1;
        Bs[tid] = (b1[tid] - m1[tid]) * sc1 + bb1[tid];
    }
    for (int i = tid; i < NPB * 33; i += ABLK) acc[i] = 0.0f;
    __syncthreads();

    const int wv = tid >> 6;                 // 0..15
    const int lane = tid & 63;
    const int f = lane & 31;
    const int esub = lane >> 5;              // 0 or 1
    const float A = As[f], Bc = Bs[f];

    // 4 edges per wave-iter: esub half handles q+esub and q+2+esub
    for (int q = elo + wv * 4; q < ehi; q += 16 * 4) {
        int e0 = q + esub;
        int e1 = q + 2 + esub;
        if (e0 < ehi) {
            unsigned pk = ebuf[e0];
            float2 p = sd[pk & 0x1FFFFu];
            float c = p.y * fmaxf(p.x * A + Bc, 0.0f);
            atomicAdd(&acc[(pk >> 17) * 33 + f], c);
        }
        if (e1 < ehi) {
            unsigned pk = ebuf[e1];
            float2 p = sd[pk & 0x1FFFFu];
            float c = p.y * fmaxf(p.x * A + Bc, 0.0f);
            atomicAdd(&acc[(pk >> 17) * 33 + f], c);
        }
    }
    __syncthreads();

    // phase 1: acc[r][k] = d_v*(self_k + acc[r][k])
    for (int idx = tid; idx < NPB * HID; idx += ABLK) {
        int r = idx >> 5, k = idx & 31;
        int node = node0 + r;
        if (node < N_NODES) {
            float2 pv = sd[node];
            float self = pv.y * fmaxf(pv.x * As[k] + Bs[k], 0.0f);
            acc[r * 33 + k] = pv.y * (self + acc[r * 33 + k]);
        }
    }
    __syncthreads();

    // phase 2: h = b2 + row @ W2; bn2+relu; store bf16 halves
    for (int idx = tid; idx < NPB * HID; idx += ABLK) {
        int r = idx >> 5, ff = idx & 31;
        int node = node0 + r;
        if (node < N_NODES) {
            float h = b2[ff];
#pragma unroll
            for (int k = 0; k < HID; ++k) h += acc[r * 33 + k] * Ws[k * HID + ff];
            float sc2 = g2[ff] * rsqrtf(v2[ff] + BN_EPS);
            float z = fmaxf((h - m2[ff]) * sc2 + bb2[ff], 0.0f);
            unsigned short o = f2bf(sd[node].y * z);
            if (ff < 16) zs3a[node * 16 + ff] = o;
            else         zs3b[node * 16 + (ff - 16)] = o;
        }
    }
}

// ---------------- layer 3: edge-centric half-feature agg ----------------

__global__ void __launch_bounds__(ABLK) k_agg3h(const int* __restrict__ bstart,
                        const unsigned* __restrict__ ebuf, const float* __restrict__ dinv,
                        const unsigned short* __restrict__ tab,   // [N][16]
                        unsigned short* __restrict__ agg3h, int halfofs) {
    __shared__ float acc[NPB * 17];          // padded stride 17
    const int b = blockIdx.x;
    const int node0 = b * NPB;
    const int elo = bstart[b], ehi = bstart[b + 1];
    const int tid = threadIdx.x;
    for (int i = tid; i < NPB * 17; i += ABLK) acc[i] = 0.0f;
    __syncthreads();

    const int wv = tid >> 6;
    const int lane = tid & 63;
    const int f = lane & 15;
    const int esub = lane >> 4;              // 0..3

    // 8 edges per wave-iter (unroll 2)
    for (int q = elo + wv * 8; q < ehi; q += 16 * 8) {
        int e0 = q + esub;
        int e1 = q + 4 + esub;
        if (e0 < ehi) {
            unsigned pk = ebuf[e0];
            float a = bf2f(tab[(pk & 0x1FFFFu) * 16 + f]);
            atomicAdd(&acc[(pk >> 17) * 17 + f], a);
        }
        if (e1 < ehi) {
            unsigned pk = ebuf[e1];
            float a = bf2f(tab[(pk & 0x1FFFFu) * 16 + f]);
            atomicAdd(&acc[(pk >> 17) * 17 + f], a);
        }
    }
    __syncthreads();

    for (int idx = tid; idx < NPB * 16; idx += ABLK) {
        int r = idx >> 4, ff = idx & 15;
        int node = node0 + r;
        if (node < N_NODES) {
            float val = bf2f(tab[node * 16 + ff]) + acc[r * 17 + ff];
            __builtin_nontemporal_store(f2bf(dinv[node] * val),
                                        &agg3h[node * HID + halfofs + ff]);
        }
    }
}

// ---------------- pool: block per graph, mean then matmul W3 ----------------

__global__ void k_pool(const unsigned short* __restrict__ agg3h,
                       const int* __restrict__ batch,
                       const float* __restrict__ W3, const float* __restrict__ b3,
                       float* __restrict__ out) {
    __shared__ float Ws[HID * HID];
    __shared__ float part[NB / HID][HID + 1];
    __shared__ float mrow[HID];
    int g = blockIdx.x;
    for (int k = threadIdx.x; k < HID * HID; k += NB) Ws[k] = W3[k];

    int lo = lbound(batch, N_NODES, g);
    int hi = lbound(batch, N_NODES, g + 1);

    int r = threadIdx.x >> 5, f = threadIdx.x & 31;
    float acc = 0.0f;
    for (int i = lo + r; i < hi; i += NB / HID)
        acc += bf2f(__builtin_nontemporal_load(&agg3h[i * HID + f]));
    part[r][f] = acc;
    __syncthreads();
    if (threadIdx.x < HID) {
        float srow = 0.0f;
#pragma unroll
        for (int k = 0; k < NB / HID; ++k) srow += part[k][threadIdx.x];
        float c = (float)(hi - lo);
        mrow[threadIdx.x] = (hi > lo) ? srow / c : 0.0f;
    }
    __syncthreads();
    if (threadIdx.x < HID) {
        int ff = threadIdx.x;
        float o = 0.0f;
        if (hi > lo) {
            o = b3[ff];
#pragma unroll
            for (int k = 0; k < HID; ++k) o += mrow[k] * Ws[k * HID + ff];
        }
        out[g * HID + ff] = o;
    }
}

// ---------------- launch ----------------

extern "C" void kernel_launch(void* const* d_in, const int* in_sizes, int n_in,
                              void* d_out, int out_size, void* d_ws, size_t ws_size,
                              hipStream_t stream) {
    const float* x     = (const float*)d_in[0];
    const int*   eidx  = (const int*)d_in[1];     // [2, E]: row0 = src, row1 = dst
    const int*   batch = (const int*)d_in[2];
    const float* W1    = (const float*)d_in[3];
    const float* b1    = (const float*)d_in[4];
    const float* bn1g  = (const float*)d_in[5];
    const float* bn1b  = (const float*)d_in[6];
    const float* bn1m  = (const float*)d_in[7];
    const float* bn1v  = (const float*)d_in[8];
    const float* W2    = (const float*)d_in[9];
    const float* b2    = (const float*)d_in[10];
    const float* bn2g  = (const float*)d_in[11];
    const float* bn2b  = (const float*)d_in[12];
    const float* bn2m  = (const float*)d_in[13];
    const float* bn2v  = (const float*)d_in[14];
    const float* W3    = (const float*)d_in[15];
    const float* b3    = (const float*)d_in[16];
    float* out = (float*)d_out;

    const int* src = eidx;
    const int* dst = eidx + N_EDGES;

    // workspace carving (256B aligned); ebuf lives through all agg kernels
    char* ws = (char*)d_ws;
    size_t off = 0;
    auto carve = [&](size_t bytes) {
        void* p = ws + off;
        off += (bytes + 255) & ~size_t(255);
        return p;
    };
    int*    bhist    = (int*)carve(NBKT * 4);
    int*    bstart   = (int*)carve((NBKT + 1) * 4);
    int*    bcursor  = (int*)carve(NBKT * 4);
    float*  dinv     = (float*)carve(N_NODES * 4);
    float*  zs1      = (float*)carve(N_NODES * 4);
    float2* sd       = (float2*)carve((size_t)N_NODES * 8);           // 0.8 MB
    unsigned*       ebuf  = (unsigned*)carve((size_t)N_EDGES * 4);    // 12.8 MB
    unsigned short* zs3a  = (unsigned short*)carve((size_t)N_NODES * 16 * 2);  // 3.2 MB
    unsigned short* zs3b  = (unsigned short*)carve((size_t)N_NODES * 16 * 2);  // 3.2 MB
    unsigned short* agg3h = (unsigned short*)carve((size_t)N_NODES * HID * 2); // 6.4 MB

    const int gPart = (N_EDGES + PART_TILE - 1) / PART_TILE;   // 782

    k_zero<<<1, NBKT, 0, stream>>>(bhist);
    k_hist<<<1024, NB, 0, stream>>>(dst, bhist);
    k_scan512<<<1, NBKT, 0, stream>>>(bhist, bstart, bcursor);
    k_partition<<<gPart, PART_THREADS, 0, stream>>>(src, dst, bcursor, ebuf);
    k_bdeg<<<NBKT, ABLK, 0, stream>>>(bstart, ebuf, x, dinv, zs1);
    k_agg1<<<NBKT, ABLK, 0, stream>>>(bstart, ebuf, dinv, zs1, sd);
    k_agg2<<<NBKT, ABLK, 0, stream>>>(bstart, ebuf, sd,
                                      W1, b1, bn1g, bn1b, bn1m, bn1v,
                                      W2, b2, bn2g, bn2b, bn2m, bn2v, zs3a, zs3b);
    k_agg3h<<<NBKT, ABLK, 0, stream>>>(bstart, ebuf, dinv, zs3a, agg3h, 0);
    k_agg3h<<<NBKT, ABLK, 0, stream>>>(bstart, ebuf, dinv, zs3b, agg3h, 16);
    k_pool<<<N_GRAPHS, NB, 0, stream>>>(agg3h, batch, W3, b3, out);
}

// Round 10
// 330.571 us; speedup vs baseline: 3.7911x; 3.7911x over previous
//
#include <hip/hip_runtime.h>

#define N_NODES 100000
#define N_EDGES 3200000
#define N_GRAPHS 1024
#define HID 32
#define BN_EPS 1e-5f
#define NB 256

#define NBKT 512
#define NPB 196                 // nodes per bucket; NBKT*NPB = 100352 >= N_NODES
#define PART_TILE 4096
#define PART_THREADS 256
#define PART_EPT (PART_TILE / PART_THREADS)   // 16

#define G2_NODES 8
#define G2_WCAP 2048            // staged edges per window (16 KB LDS)
#define G2_EPT (G2_WCAP / NB)   // 8 entries per thread

// ---------------- helpers ----------------

__device__ __forceinline__ int lbound(const int* __restrict__ a, int n, int key) {
    int lo = 0, hi = n;
    while (lo < hi) {
        int mid = (lo + hi) >> 1;
        if (a[mid] < key) lo = mid + 1; else hi = mid;
    }
    return lo;
}

__device__ __forceinline__ float bf2f(unsigned short h) {
    return __uint_as_float((unsigned)h << 16);
}
__device__ __forceinline__ unsigned short f2bf(float x) {   // round-to-nearest-even
    unsigned u = __float_as_uint(x);
    u += 0x7fffu + ((u >> 16) & 1u);
    return (unsigned short)(u >> 16);
}

// ---------------- CSR build (bucketed multisplit, 4B-packed edges) ----------------

__global__ void k_zero(int* __restrict__ bhist) {
    bhist[threadIdx.x] = 0;
}

__global__ void k_hist(const int* __restrict__ dst, int* __restrict__ bhist) {
    __shared__ int h[NBKT];
    for (int i = threadIdx.x; i < NBKT; i += NB) h[i] = 0;
    __syncthreads();
    for (int e = blockIdx.x * NB + threadIdx.x; e < N_EDGES; e += gridDim.x * NB)
        atomicAdd(&h[__builtin_nontemporal_load(&dst[e]) / NPB], 1);
    __syncthreads();
    for (int i = threadIdx.x; i < NBKT; i += NB)
        if (h[i]) atomicAdd(&bhist[i], h[i]);
}

// single block of NBKT threads: exclusive scan -> bstart, bcursor
__global__ void k_scan512(const int* __restrict__ bhist, int* __restrict__ bstart,
                          int* __restrict__ bcursor) {
    __shared__ int sm[NBKT];
    int t = threadIdx.x;
    int orig = bhist[t];
    sm[t] = orig;
    __syncthreads();
    for (int off = 1; off < NBKT; off <<= 1) {
        int v = (t >= off) ? sm[t - off] : 0;
        __syncthreads();
        sm[t] += v;
        __syncthreads();
    }
    int ex = sm[t] - orig;
    bstart[t] = ex;
    bcursor[t] = ex;
    if (t == NBKT - 1) bstart[NBKT] = sm[t];
}

// partition edges into bucket-major ebuf; entry = (dst_local << 17) | src  (4B)
__global__ void k_partition(const int* __restrict__ src, const int* __restrict__ dst,
                            int* __restrict__ bcursor, unsigned* __restrict__ ebuf) {
    __shared__ int lh[NBKT];
    __shared__ int lcur[NBKT];
    const int tile0 = blockIdx.x * PART_TILE;
    for (int i = threadIdx.x; i < NBKT; i += PART_THREADS) lh[i] = 0;
    __syncthreads();
    int s[PART_EPT], bk[PART_EPT], dl[PART_EPT];
#pragma unroll
    for (int k = 0; k < PART_EPT; ++k) {
        int e = tile0 + k * PART_THREADS + threadIdx.x;
        bool ok = (e < N_EDGES);
        int sv = ok ? __builtin_nontemporal_load(&src[e]) : 0;
        int dv = ok ? __builtin_nontemporal_load(&dst[e]) : 0;
        s[k] = sv;
        bk[k] = ok ? (dv / NPB) : -1;
        dl[k] = dv - bk[k] * NPB;
        if (ok) atomicAdd(&lh[bk[k]], 1);
    }
    __syncthreads();
    for (int i = threadIdx.x; i < NBKT; i += PART_THREADS)
        lcur[i] = lh[i] ? atomicAdd(&bcursor[i], lh[i]) : 0;
    __syncthreads();
#pragma unroll
    for (int k = 0; k < PART_EPT; ++k) {
        if (bk[k] >= 0) {
            int pos = atomicAdd(&lcur[bk[k]], 1);
            unsigned pk = ((unsigned)dl[k] << 17) | (unsigned)s[k];
            __builtin_nontemporal_store(pk, &ebuf[pos]);
        }
    }
}

// per-bucket: node histogram -> rowstart/deg/dinv/zs1, then scatter csr
__global__ void k_bucket(const int* __restrict__ bstart,
                         const unsigned* __restrict__ ebuf,
                         const float* __restrict__ x,
                         int* __restrict__ rowstart, int* __restrict__ deg,
                         float* __restrict__ dinv, float* __restrict__ zs1,
                         int* __restrict__ csr) {
    __shared__ int hist[NPB];
    __shared__ int sm[256];
    __shared__ int lcur[NPB];
    const int b = blockIdx.x;
    const int node0 = b * NPB;
    const int nn = N_NODES - node0;
    const int elo = bstart[b], ehi = bstart[b + 1];
    const int t = threadIdx.x;

    for (int i = t; i < NPB; i += blockDim.x) hist[i] = 0;
    __syncthreads();
    for (int e = elo + t; e < ehi; e += blockDim.x)
        atomicAdd(&hist[ebuf[e] >> 17], 1);
    __syncthreads();
    int orig = 0;
    if (t < 256) { orig = (t < NPB) ? hist[t] : 0; sm[t] = orig; }
    __syncthreads();
    for (int off = 1; off < 256; off <<= 1) {
        int v = 0;
        if (t < 256 && t >= off) v = sm[t - off];
        __syncthreads();
        if (t < 256) sm[t] += v;
        __syncthreads();
    }
    if (t < NPB) {
        int ex = sm[t] - orig;
        lcur[t] = ex;
        if (t < nn) {
            int node = node0 + t;
            rowstart[node] = elo + ex;
            deg[node] = orig;
            float di = rsqrtf((float)(orig + 1));
            dinv[node] = di;
            zs1[node] = di * x[node];
        }
    }
    __syncthreads();
    for (int e = elo + t; e < ehi; e += blockDim.x) {
        unsigned pk = ebuf[e];
        int pos = atomicAdd(&lcur[pk >> 17], 1);
        csr[elo + pos] = (int)(pk & 0x1FFFFu);
    }
}

// ---------------- layer 1: scalar gather -> sd = (s, dinv) ----------------

__global__ void k_gather1(const int* __restrict__ rowstart, const int* __restrict__ deg,
                          const int* __restrict__ csr, const float* __restrict__ dinv,
                          const float* __restrict__ zs1, float2* __restrict__ sd) {
    int v = blockIdx.x * NB + threadIdx.x;
    if (v < N_NODES) {
        int lo = rowstart[v], n = deg[v];
        float acc = zs1[v];
        int j = 0;
        for (; j + 4 <= n; j += 4) {
            int u0 = __builtin_nontemporal_load(&csr[lo + j]);
            int u1 = __builtin_nontemporal_load(&csr[lo + j + 1]);
            int u2 = __builtin_nontemporal_load(&csr[lo + j + 2]);
            int u3 = __builtin_nontemporal_load(&csr[lo + j + 3]);
            float a0 = zs1[u0], a1 = zs1[u1], a2 = zs1[u2], a3 = zs1[u3];
            acc += (a0 + a1) + (a2 + a3);
        }
        for (; j < n; ++j) acc += zs1[csr[lo + j]];
        float di = dinv[v];
        sd[v] = make_float2(di * acc, di);
    }
}

// ---------------- layer 2: LDS-staged rank-1 gather, async reg prefetch ----------------
// Block = 8 nodes; block's edges contiguous in CSR. Window w+1 is gathered into
// registers while window w is consumed from LDS (T14 async-stage split).
__global__ void k_gather2(const int* __restrict__ rowstart, const int* __restrict__ deg,
                          const int* __restrict__ csr, const float2* __restrict__ sd,
                          const float* __restrict__ W1, const float* __restrict__ b1,
                          const float* __restrict__ g1, const float* __restrict__ bb1,
                          const float* __restrict__ m1, const float* __restrict__ v1,
                          const float* __restrict__ W2,
                          const float* __restrict__ b2, const float* __restrict__ g2,
                          const float* __restrict__ bb2, const float* __restrict__ m2,
                          const float* __restrict__ v2,
                          unsigned short* __restrict__ zs3a,
                          unsigned short* __restrict__ zs3b) {
    __shared__ float Ws[HID * HID];
    __shared__ float2 sde[G2_WCAP];
    __shared__ float rowbuf[G2_NODES][HID + 1];
    __shared__ int sb[2];
    const int tid = threadIdx.x;
    for (int k = tid; k < HID * HID; k += NB) Ws[k] = W2[k];

    const int r = tid >> 5, f = tid & 31;
    const int v = blockIdx.x * G2_NODES + r;
    const bool valid = v < N_NODES;

    if (tid == 0) {
        int first = blockIdx.x * G2_NODES;
        int last = min(first + G2_NODES - 1, N_NODES - 1);
        sb[0] = rowstart[first];
        sb[1] = rowstart[last] + deg[last];
    }

    const float sc1 = g1[f] * rsqrtf(v1[f] + BN_EPS);
    const float A = W1[f] * sc1;
    const float Bc = (b1[f] - m1[f]) * sc1 + bb1[f];

    float di = 0.0f, acc = 0.0f;
    int rs = 0, re = 0;
    if (valid) {
        rs = rowstart[v];
        re = rs + deg[v];
        float2 pv = sd[v];
        di = pv.y;
        acc = di * fmaxf(pv.x * A + Bc, 0.0f);   // self-loop term zs2[v]
    }
    __syncthreads();
    const int blo = sb[0], bhi = sb[1];

    // prologue: gather window 0 into registers
    float2 pre[G2_EPT];
    {
        int wn0 = min(G2_WCAP, bhi - blo);
#pragma unroll
        for (int k = 0; k < G2_EPT; ++k) {
            int i = k * NB + tid;
            pre[k] = (i < wn0)
                ? sd[__builtin_nontemporal_load(&csr[blo + i])]
                : make_float2(0.0f, 0.0f);
        }
    }

    for (int w = blo; w < bhi; w += G2_WCAP) {
        const int wn = min(G2_WCAP, bhi - w);
        // write staged regs -> LDS
#pragma unroll
        for (int k = 0; k < G2_EPT; ++k) {
            int i = k * NB + tid;
            if (i < wn) sde[i] = pre[k];
        }
        // prefetch next window into regs (overlaps with consume below)
        const int wnext = w + G2_WCAP;
        if (wnext < bhi) {
            int wn2 = min(G2_WCAP, bhi - wnext);
#pragma unroll
            for (int k = 0; k < G2_EPT; ++k) {
                int i = k * NB + tid;
                pre[k] = (i < wn2)
                    ? sd[__builtin_nontemporal_load(&csr[wnext + i])]
                    : make_float2(0.0f, 0.0f);
            }
        }
        __syncthreads();
        int jlo = max(rs, w) - w;
        int jhi = min(re, w + wn) - w;
        int j = jlo;
        for (; j + 4 <= jhi; j += 4) {
            float2 p0 = sde[j], p1 = sde[j + 1], p2 = sde[j + 2], p3 = sde[j + 3];
            float a0 = p0.y * fmaxf(p0.x * A + Bc, 0.0f);
            float a1 = p1.y * fmaxf(p1.x * A + Bc, 0.0f);
            float a2 = p2.y * fmaxf(p2.x * A + Bc, 0.0f);
            float a3 = p3.y * fmaxf(p3.x * A + Bc, 0.0f);
            acc += (a0 + a1) + (a2 + a3);
        }
        for (; j < jhi; ++j) {
            float2 p = sde[j];
            acc += p.y * fmaxf(p.x * A + Bc, 0.0f);
        }
        __syncthreads();
    }
    acc *= di;                 // agg2[v,f]
    rowbuf[r][f] = acc;
    __syncthreads();
    if (valid) {
        float h = b2[f];
#pragma unroll
        for (int k = 0; k < HID; ++k) h += rowbuf[r][k] * Ws[k * HID + f];
        float sc2 = g2[f] * rsqrtf(v2[f] + BN_EPS);
        float z = fmaxf((h - m2[f]) * sc2 + bb2[f], 0.0f);
        unsigned short o = f2bf(di * z);
        if (f < 16) zs3a[v * 16 + f] = o;
        else        zs3b[v * 16 + (f - 16)] = o;
    }
}

// ---------------- layer 3: half-feature gather (3.2MB table, L2-resident) ----------------

__global__ void k_gather3h(const int* __restrict__ rowstart, const int* __restrict__ deg,
                           const int* __restrict__ csr, const float* __restrict__ dinv,
                           const unsigned short* __restrict__ tab,   // [N][16]
                           unsigned short* __restrict__ agg3h, int halfofs) {
    int t = blockIdx.x * NB + threadIdx.x;
    int v = t >> 4, f = t & 15;
    if (v < N_NODES) {
        int lo = rowstart[v], n = deg[v];
        float acc = bf2f(tab[v * 16 + f]);
        int j = 0;
        for (; j + 8 <= n; j += 8) {
            int u0 = __builtin_nontemporal_load(&csr[lo + j]);
            int u1 = __builtin_nontemporal_load(&csr[lo + j + 1]);
            int u2 = __builtin_nontemporal_load(&csr[lo + j + 2]);
            int u3 = __builtin_nontemporal_load(&csr[lo + j + 3]);
            int u4 = __builtin_nontemporal_load(&csr[lo + j + 4]);
            int u5 = __builtin_nontemporal_load(&csr[lo + j + 5]);
            int u6 = __builtin_nontemporal_load(&csr[lo + j + 6]);
            int u7 = __builtin_nontemporal_load(&csr[lo + j + 7]);
            float a0 = bf2f(tab[u0 * 16 + f]);
            float a1 = bf2f(tab[u1 * 16 + f]);
            float a2 = bf2f(tab[u2 * 16 + f]);
            float a3 = bf2f(tab[u3 * 16 + f]);
            float a4 = bf2f(tab[u4 * 16 + f]);
            float a5 = bf2f(tab[u5 * 16 + f]);
            float a6 = bf2f(tab[u6 * 16 + f]);
            float a7 = bf2f(tab[u7 * 16 + f]);
            acc += ((a0 + a1) + (a2 + a3)) + ((a4 + a5) + (a6 + a7));
        }
        for (; j < n; ++j) acc += bf2f(tab[csr[lo + j] * 16 + f]);
        __builtin_nontemporal_store(f2bf(dinv[v] * acc), &agg3h[v * HID + halfofs + f]);
    }
}

// ---------------- pool: block per graph, mean then matmul W3 ----------------

__global__ void k_pool(const unsigned short* __restrict__ agg3h,
                       const int* __restrict__ batch,
                       const float* __restrict__ W3, const float* __restrict__ b3,
                       float* __restrict__ out) {
    __shared__ float Ws[HID * HID];
    __shared__ float part[NB / HID][HID + 1];
    __shared__ float mrow[HID];
    int g = blockIdx.x;
    for (int k = threadIdx.x; k < HID * HID; k += NB) Ws[k] = W3[k];

    int lo = lbound(batch, N_NODES, g);
    int hi = lbound(batch, N_NODES, g + 1);

    int r = threadIdx.x >> 5, f = threadIdx.x & 31;
    float acc = 0.0f;
    for (int i = lo + r; i < hi; i += NB / HID)
        acc += bf2f(__builtin_nontemporal_load(&agg3h[i * HID + f]));
    part[r][f] = acc;
    __syncthreads();
    if (threadIdx.x < HID) {
        float srow = 0.0f;
#pragma unroll
        for (int k = 0; k < NB / HID; ++k) srow += part[k][threadIdx.x];
        float c = (float)(hi - lo);
        mrow[threadIdx.x] = (hi > lo) ? srow / c : 0.0f;
    }
    __syncthreads();
    if (threadIdx.x < HID) {
        int ff = threadIdx.x;
        float o = 0.0f;
        if (hi > lo) {
            o = b3[ff];
#pragma unroll
            for (int k = 0; k < HID; ++k) o += mrow[k] * Ws[k * HID + ff];
        }
        out[g * HID + ff] = o;
    }
}

// ---------------- launch ----------------

extern "C" void kernel_launch(void* const* d_in, const int* in_sizes, int n_in,
                              void* d_out, int out_size, void* d_ws, size_t ws_size,
                              hipStream_t stream) {
    const float* x     = (const float*)d_in[0];
    const int*   eidx  = (const int*)d_in[1];     // [2, E]: row0 = src, row1 = dst
    const int*   batch = (const int*)d_in[2];
    const float* W1    = (const float*)d_in[3];
    const float* b1    = (const float*)d_in[4];
    const float* bn1g  = (const float*)d_in[5];
    const float* bn1b  = (const float*)d_in[6];
    const float* bn1m  = (const float*)d_in[7];
    const float* bn1v  = (const float*)d_in[8];
    const float* W2    = (const float*)d_in[9];
    const float* b2    = (const float*)d_in[10];
    const float* bn2g  = (const float*)d_in[11];
    const float* bn2b  = (const float*)d_in[12];
    const float* bn2m  = (const float*)d_in[13];
    const float* bn2v  = (const float*)d_in[14];
    const float* W3    = (const float*)d_in[15];
    const float* b3    = (const float*)d_in[16];
    float* out = (float*)d_out;

    const int* src = eidx;
    const int* dst = eidx + N_EDGES;

    // workspace carving (256B aligned)
    char* ws = (char*)d_ws;
    size_t off = 0;
    auto carve = [&](size_t bytes) {
        void* p = ws + off;
        off += (bytes + 255) & ~size_t(255);
        return p;
    };
    int*    bhist    = (int*)carve(NBKT * 4);
    int*    bstart   = (int*)carve((NBKT + 1) * 4);
    int*    bcursor  = (int*)carve(NBKT * 4);
    int*    rowstart = (int*)carve(N_NODES * 4);
    int*    deg      = (int*)carve(N_NODES * 4);
    float*  dinv     = (float*)carve(N_NODES * 4);
    float*  zs1      = (float*)carve(N_NODES * 4);
    float2* sd       = (float2*)carve((size_t)N_NODES * 8);        // 0.8 MB (L2-resident)
    int*    csr      = (int*)carve((size_t)N_EDGES * 4);           // 12.8 MB
    // 12.8 MB region: ebuf dead after k_bucket; then zs3a(3.2) | zs3b(3.2) | agg3h(6.4)
    char*   region   = (char*)carve((size_t)N_EDGES * 4);
    unsigned*       ebuf  = (unsigned*)region;
    unsigned short* zs3a  = (unsigned short*)region;
    unsigned short* zs3b  = (unsigned short*)(region + (size_t)N_NODES * 16 * 2);
    unsigned short* agg3h = (unsigned short*)(region + (size_t)N_NODES * 32 * 2);

    const int gN    = (N_NODES + NB - 1) / NB;                 // 391
    const int gG2   = (N_NODES + G2_NODES - 1) / G2_NODES;     // 12500
    const int gG3   = (N_NODES * 16 + NB - 1) / NB;            // 6250
    const int gPart = (N_EDGES + PART_TILE - 1) / PART_TILE;   // 782

    k_zero<<<1, NBKT, 0, stream>>>(bhist);
    k_hist<<<1024, NB, 0, stream>>>(dst, bhist);
    k_scan512<<<1, NBKT, 0, stream>>>(bhist, bstart, bcursor);
    k_partition<<<gPart, PART_THREADS, 0, stream>>>(src, dst, bcursor, ebuf);
    k_bucket<<<NBKT, 512, 0, stream>>>(bstart, ebuf, x, rowstart, deg, dinv, zs1, csr);
    k_gather1<<<gN, NB, 0, stream>>>(rowstart, deg, csr, dinv, zs1, sd);
    k_gather2<<<gG2, NB, 0, stream>>>(rowstart, deg, csr, sd,
                                      W1, b1, bn1g, bn1b, bn1m, bn1v,
                                      W2, b2, bn2g, bn2b, bn2m, bn2v, zs3a, zs3b);
    k_gather3h<<<gG3, NB, 0, stream>>>(rowstart, deg, csr, dinv, zs3a, agg3h, 0);
    k_gather3h<<<gG3, NB, 0, stream>>>(rowstart, deg, csr, dinv, zs3b, agg3h, 16);
    k_pool<<<N_GRAPHS, NB, 0, stream>>>(agg3h, batch, W3, b3, out);
}

// Round 11
// 265.270 us; speedup vs baseline: 4.7243x; 1.2462x over previous
//
#include <hip/hip_runtime.h>

#define N_NODES 100000
#define N_EDGES 3200000
#define N_GRAPHS 1024
#define HID 32
#define BN_EPS 1e-5f
#define NB 256

#define NBKT 512
#define NPB 196                 // nodes per bucket; NBKT*NPB = 100352 >= N_NODES
#define PART_TILE 4096
#define PART_THREADS 256
#define PART_EPT (PART_TILE / PART_THREADS)   // 16

#define G2_NODES 8
#define G2_WCAP 2048            // staged edges per window (16 KB LDS)
#define G2_EPT (G2_WCAP / NB)   // 8 entries per thread

// ---------------- helpers ----------------

__device__ __forceinline__ int lbound(const int* __restrict__ a, int n, int key) {
    int lo = 0, hi = n;
    while (lo < hi) {
        int mid = (lo + hi) >> 1;
        if (a[mid] < key) lo = mid + 1; else hi = mid;
    }
    return lo;
}

__device__ __forceinline__ float bf2f(unsigned short h) {
    return __uint_as_float((unsigned)h << 16);
}
__device__ __forceinline__ unsigned short f2bf(float x) {   // round-to-nearest-even
    unsigned u = __float_as_uint(x);
    u += 0x7fffu + ((u >> 16) & 1u);
    return (unsigned short)(u >> 16);
}

// ---------------- CSR build (bucketed multisplit, 4B-packed edges) ----------------

__global__ void k_zero(int* __restrict__ bhist) {
    bhist[threadIdx.x] = 0;
}

__global__ void k_hist(const int* __restrict__ dst, int* __restrict__ bhist) {
    __shared__ int h[NBKT];
    for (int i = threadIdx.x; i < NBKT; i += NB) h[i] = 0;
    __syncthreads();
    for (int e = blockIdx.x * NB + threadIdx.x; e < N_EDGES; e += gridDim.x * NB)
        atomicAdd(&h[__builtin_nontemporal_load(&dst[e]) / NPB], 1);
    __syncthreads();
    for (int i = threadIdx.x; i < NBKT; i += NB)
        if (h[i]) atomicAdd(&bhist[i], h[i]);
}

// single block of NBKT threads: exclusive scan -> bstart, bcursor
__global__ void k_scan512(const int* __restrict__ bhist, int* __restrict__ bstart,
                          int* __restrict__ bcursor) {
    __shared__ int sm[NBKT];
    int t = threadIdx.x;
    int orig = bhist[t];
    sm[t] = orig;
    __syncthreads();
    for (int off = 1; off < NBKT; off <<= 1) {
        int v = (t >= off) ? sm[t - off] : 0;
        __syncthreads();
        sm[t] += v;
        __syncthreads();
    }
    int ex = sm[t] - orig;
    bstart[t] = ex;
    bcursor[t] = ex;
    if (t == NBKT - 1) bstart[NBKT] = sm[t];
}

// partition edges into bucket-major ebuf; entry = (dst_local << 17) | src  (4B)
// NOTE: plain store for ebuf — scattered 4B writes MUST go through L2 for
// write-combining (R10: NT store here = 110 MB HBM write-through, 112 µs).
__global__ void k_partition(const int* __restrict__ src, const int* __restrict__ dst,
                            int* __restrict__ bcursor, unsigned* __restrict__ ebuf) {
    __shared__ int lh[NBKT];
    __shared__ int lcur[NBKT];
    const int tile0 = blockIdx.x * PART_TILE;
    for (int i = threadIdx.x; i < NBKT; i += PART_THREADS) lh[i] = 0;
    __syncthreads();
    int s[PART_EPT], bk[PART_EPT], dl[PART_EPT];
#pragma unroll
    for (int k = 0; k < PART_EPT; ++k) {
        int e = tile0 + k * PART_THREADS + threadIdx.x;
        bool ok = (e < N_EDGES);
        int sv = ok ? __builtin_nontemporal_load(&src[e]) : 0;
        int dv = ok ? __builtin_nontemporal_load(&dst[e]) : 0;
        s[k] = sv;
        bk[k] = ok ? (dv / NPB) : -1;
        dl[k] = dv - bk[k] * NPB;
        if (ok) atomicAdd(&lh[bk[k]], 1);
    }
    __syncthreads();
    for (int i = threadIdx.x; i < NBKT; i += PART_THREADS)
        lcur[i] = lh[i] ? atomicAdd(&bcursor[i], lh[i]) : 0;
    __syncthreads();
#pragma unroll
    for (int k = 0; k < PART_EPT; ++k) {
        if (bk[k] >= 0) {
            int pos = atomicAdd(&lcur[bk[k]], 1);
            ebuf[pos] = ((unsigned)dl[k] << 17) | (unsigned)s[k];
        }
    }
}

// per-bucket: node histogram -> rowstart/deg/dinv/zs1, then scatter csr
__global__ void k_bucket(const int* __restrict__ bstart,
                         const unsigned* __restrict__ ebuf,
                         const float* __restrict__ x,
                         int* __restrict__ rowstart, int* __restrict__ deg,
                         float* __restrict__ dinv, float* __restrict__ zs1,
                         int* __restrict__ csr) {
    __shared__ int hist[NPB];
    __shared__ int sm[256];
    __shared__ int lcur[NPB];
    const int b = blockIdx.x;
    const int node0 = b * NPB;
    const int nn = N_NODES - node0;
    const int elo = bstart[b], ehi = bstart[b + 1];
    const int t = threadIdx.x;

    for (int i = t; i < NPB; i += blockDim.x) hist[i] = 0;
    __syncthreads();
    for (int e = elo + t; e < ehi; e += blockDim.x)
        atomicAdd(&hist[ebuf[e] >> 17], 1);
    __syncthreads();
    int orig = 0;
    if (t < 256) { orig = (t < NPB) ? hist[t] : 0; sm[t] = orig; }
    __syncthreads();
    for (int off = 1; off < 256; off <<= 1) {
        int v = 0;
        if (t < 256 && t >= off) v = sm[t - off];
        __syncthreads();
        if (t < 256) sm[t] += v;
        __syncthreads();
    }
    if (t < NPB) {
        int ex = sm[t] - orig;
        lcur[t] = ex;
        if (t < nn) {
            int node = node0 + t;
            rowstart[node] = elo + ex;
            deg[node] = orig;
            float di = rsqrtf((float)(orig + 1));
            dinv[node] = di;
            zs1[node] = di * x[node];
        }
    }
    __syncthreads();
    for (int e = elo + t; e < ehi; e += blockDim.x) {
        unsigned pk = ebuf[e];
        int pos = atomicAdd(&lcur[pk >> 17], 1);
        csr[elo + pos] = (int)(pk & 0x1FFFFu);
    }
}

// ---------------- layer 1: scalar gather -> sd = (s, dinv) ----------------

__global__ void k_gather1(const int* __restrict__ rowstart, const int* __restrict__ deg,
                          const int* __restrict__ csr, const float* __restrict__ dinv,
                          const float* __restrict__ zs1, float2* __restrict__ sd) {
    int v = blockIdx.x * NB + threadIdx.x;
    if (v < N_NODES) {
        int lo = rowstart[v], n = deg[v];
        float acc = zs1[v];
        int j = 0;
        for (; j + 4 <= n; j += 4) {
            int u0 = __builtin_nontemporal_load(&csr[lo + j]);
            int u1 = __builtin_nontemporal_load(&csr[lo + j + 1]);
            int u2 = __builtin_nontemporal_load(&csr[lo + j + 2]);
            int u3 = __builtin_nontemporal_load(&csr[lo + j + 3]);
            float a0 = zs1[u0], a1 = zs1[u1], a2 = zs1[u2], a3 = zs1[u3];
            acc += (a0 + a1) + (a2 + a3);
        }
        for (; j < n; ++j) acc += zs1[csr[lo + j]];
        float di = dinv[v];
        sd[v] = make_float2(di * acc, di);
    }
}

// ---------------- layer 2: LDS-staged rank-1 gather, async reg prefetch ----------------
// Block = 8 nodes; block's edges contiguous in CSR. Window w+1 is gathered into
// registers while window w is consumed from LDS (T14 async-stage split).
__global__ void k_gather2(const int* __restrict__ rowstart, const int* __restrict__ deg,
                          const int* __restrict__ csr, const float2* __restrict__ sd,
                          const float* __restrict__ W1, const float* __restrict__ b1,
                          const float* __restrict__ g1, const float* __restrict__ bb1,
                          const float* __restrict__ m1, const float* __restrict__ v1,
                          const float* __restrict__ W2,
                          const float* __restrict__ b2, const float* __restrict__ g2,
                          const float* __restrict__ bb2, const float* __restrict__ m2,
                          const float* __restrict__ v2,
                          unsigned short* __restrict__ zs3a,
                          unsigned short* __restrict__ zs3b) {
    __shared__ float Ws[HID * HID];
    __shared__ float2 sde[G2_WCAP];
    __shared__ float rowbuf[G2_NODES][HID + 1];
    __shared__ int sb[2];
    const int tid = threadIdx.x;
    for (int k = tid; k < HID * HID; k += NB) Ws[k] = W2[k];

    const int r = tid >> 5, f = tid & 31;
    const int v = blockIdx.x * G2_NODES + r;
    const bool valid = v < N_NODES;

    if (tid == 0) {
        int first = blockIdx.x * G2_NODES;
        int last = min(first + G2_NODES - 1, N_NODES - 1);
        sb[0] = rowstart[first];
        sb[1] = rowstart[last] + deg[last];
    }

    const float sc1 = g1[f] * rsqrtf(v1[f] + BN_EPS);
    const float A = W1[f] * sc1;
    const float Bc = (b1[f] - m1[f]) * sc1 + bb1[f];

    float di = 0.0f, acc = 0.0f;
    int rs = 0, re = 0;
    if (valid) {
        rs = rowstart[v];
        re = rs + deg[v];
        float2 pv = sd[v];
        di = pv.y;
        acc = di * fmaxf(pv.x * A + Bc, 0.0f);   // self-loop term zs2[v]
    }
    __syncthreads();
    const int blo = sb[0], bhi = sb[1];

    // prologue: gather window 0 into registers
    float2 pre[G2_EPT];
    {
        int wn0 = min(G2_WCAP, bhi - blo);
#pragma unroll
        for (int k = 0; k < G2_EPT; ++k) {
            int i = k * NB + tid;
            pre[k] = (i < wn0)
                ? sd[__builtin_nontemporal_load(&csr[blo + i])]
                : make_float2(0.0f, 0.0f);
        }
    }

    for (int w = blo; w < bhi; w += G2_WCAP) {
        const int wn = min(G2_WCAP, bhi - w);
        // write staged regs -> LDS
#pragma unroll
        for (int k = 0; k < G2_EPT; ++k) {
            int i = k * NB + tid;
            if (i < wn) sde[i] = pre[k];
        }
        // prefetch next window into regs (overlaps with consume below)
        const int wnext = w + G2_WCAP;
        if (wnext < bhi) {
            int wn2 = min(G2_WCAP, bhi - wnext);
#pragma unroll
            for (int k = 0; k < G2_EPT; ++k) {
                int i = k * NB + tid;
                pre[k] = (i < wn2)
                    ? sd[__builtin_nontemporal_load(&csr[wnext + i])]
                    : make_float2(0.0f, 0.0f);
            }
        }
        __syncthreads();
        int jlo = max(rs, w) - w;
        int jhi = min(re, w + wn) - w;
        int j = jlo;
        for (; j + 4 <= jhi; j += 4) {
            float2 p0 = sde[j], p1 = sde[j + 1], p2 = sde[j + 2], p3 = sde[j + 3];
            float a0 = p0.y * fmaxf(p0.x * A + Bc, 0.0f);
            float a1 = p1.y * fmaxf(p1.x * A + Bc, 0.0f);
            float a2 = p2.y * fmaxf(p2.x * A + Bc, 0.0f);
            float a3 = p3.y * fmaxf(p3.x * A + Bc, 0.0f);
            acc += (a0 + a1) + (a2 + a3);
        }
        for (; j < jhi; ++j) {
            float2 p = sde[j];
            acc += p.y * fmaxf(p.x * A + Bc, 0.0f);
        }
        __syncthreads();
    }
    acc *= di;                 // agg2[v,f]
    rowbuf[r][f] = acc;
    __syncthreads();
    if (valid) {
        float h = b2[f];
#pragma unroll
        for (int k = 0; k < HID; ++k) h += rowbuf[r][k] * Ws[k * HID + f];
        float sc2 = g2[f] * rsqrtf(v2[f] + BN_EPS);
        float z = fmaxf((h - m2[f]) * sc2 + bb2[f], 0.0f);
        unsigned short o = f2bf(di * z);
        if (f < 16) zs3a[v * 16 + f] = o;
        else        zs3b[v * 16 + (f - 16)] = o;
    }
}

// ---------------- layer 3: half-feature gather (3.2MB table, L2-resident) ----------------

__global__ void k_gather3h(const int* __restrict__ rowstart, const int* __restrict__ deg,
                           const int* __restrict__ csr, const float* __restrict__ dinv,
                           const unsigned short* __restrict__ tab,   // [N][16]
                           unsigned short* __restrict__ agg3h, int halfofs) {
    int t = blockIdx.x * NB + threadIdx.x;
    int v = t >> 4, f = t & 15;
    if (v < N_NODES) {
        int lo = rowstart[v], n = deg[v];
        float acc = bf2f(tab[v * 16 + f]);
        int j = 0;
        for (; j + 8 <= n; j += 8) {
            int u0 = __builtin_nontemporal_load(&csr[lo + j]);
            int u1 = __builtin_nontemporal_load(&csr[lo + j + 1]);
            int u2 = __builtin_nontemporal_load(&csr[lo + j + 2]);
            int u3 = __builtin_nontemporal_load(&csr[lo + j + 3]);
            int u4 = __builtin_nontemporal_load(&csr[lo + j + 4]);
            int u5 = __builtin_nontemporal_load(&csr[lo + j + 5]);
            int u6 = __builtin_nontemporal_load(&csr[lo + j + 6]);
            int u7 = __builtin_nontemporal_load(&csr[lo + j + 7]);
            float a0 = bf2f(tab[u0 * 16 + f]);
            float a1 = bf2f(tab[u1 * 16 + f]);
            float a2 = bf2f(tab[u2 * 16 + f]);
            float a3 = bf2f(tab[u3 * 16 + f]);
            float a4 = bf2f(tab[u4 * 16 + f]);
            float a5 = bf2f(tab[u5 * 16 + f]);
            float a6 = bf2f(tab[u6 * 16 + f]);
            float a7 = bf2f(tab[u7 * 16 + f]);
            acc += ((a0 + a1) + (a2 + a3)) + ((a4 + a5) + (a6 + a7));
        }
        for (; j < n; ++j) acc += bf2f(tab[csr[lo + j] * 16 + f]);
        __builtin_nontemporal_store(f2bf(dinv[v] * acc), &agg3h[v * HID + halfofs + f]);
    }
}

// ---------------- pool: block per graph, mean then matmul W3 ----------------

__global__ void k_pool(const unsigned short* __restrict__ agg3h,
                       const int* __restrict__ batch,
                       const float* __restrict__ W3, const float* __restrict__ b3,
                       float* __restrict__ out) {
    __shared__ float Ws[HID * HID];
    __shared__ float part[NB / HID][HID + 1];
    __shared__ float mrow[HID];
    int g = blockIdx.x;
    for (int k = threadIdx.x; k < HID * HID; k += NB) Ws[k] = W3[k];

    int lo = lbound(batch, N_NODES, g);
    int hi = lbound(batch, N_NODES, g + 1);

    int r = threadIdx.x >> 5, f = threadIdx.x & 31;
    float acc = 0.0f;
    for (int i = lo + r; i < hi; i += NB / HID)
        acc += bf2f(__builtin_nontemporal_load(&agg3h[i * HID + f]));
    part[r][f] = acc;
    __syncthreads();
    if (threadIdx.x < HID) {
        float srow = 0.0f;
#pragma unroll
        for (int k = 0; k < NB / HID; ++k) srow += part[k][threadIdx.x];
        float c = (float)(hi - lo);
        mrow[threadIdx.x] = (hi > lo) ? srow / c : 0.0f;
    }
    __syncthreads();
    if (threadIdx.x < HID) {
        int ff = threadIdx.x;
        float o = 0.0f;
        if (hi > lo) {
            o = b3[ff];
#pragma unroll
            for (int k = 0; k < HID; ++k) o += mrow[k] * Ws[k * HID + ff];
        }
        out[g * HID + ff] = o;
    }
}

// ---------------- launch ----------------

extern "C" void kernel_launch(void* const* d_in, const int* in_sizes, int n_in,
                              void* d_out, int out_size, void* d_ws, size_t ws_size,
                              hipStream_t stream) {
    const float* x     = (const float*)d_in[0];
    const int*   eidx  = (const int*)d_in[1];     // [2, E]: row0 = src, row1 = dst
    const int*   batch = (const int*)d_in[2];
    const float* W1    = (const float*)d_in[3];
    const float* b1    = (const float*)d_in[4];
    const float* bn1g  = (const float*)d_in[5];
    const float* bn1b  = (const float*)d_in[6];
    const float* bn1m  = (const float*)d_in[7];
    const float* bn1v  = (const float*)d_in[8];
    const float* W2    = (const float*)d_in[9];
    const float* b2    = (const float*)d_in[10];
    const float* bn2g  = (const float*)d_in[11];
    const float* bn2b  = (const float*)d_in[12];
    const float* bn2m  = (const float*)d_in[13];
    const float* bn2v  = (const float*)d_in[14];
    const float* W3    = (const float*)d_in[15];
    const float* b3    = (const float*)d_in[16];
    float* out = (float*)d_out;

    const int* src = eidx;
    const int* dst = eidx + N_EDGES;

    // workspace carving (256B aligned)
    char* ws = (char*)d_ws;
    size_t off = 0;
    auto carve = [&](size_t bytes) {
        void* p = ws + off;
        off += (bytes + 255) & ~size_t(255);
        return p;
    };
    int*    bhist    = (int*)carve(NBKT * 4);
    int*    bstart   = (int*)carve((NBKT + 1) * 4);
    int*    bcursor  = (int*)carve(NBKT * 4);
    int*    rowstart = (int*)carve(N_NODES * 4);
    int*    deg      = (int*)carve(N_NODES * 4);
    float*  dinv     = (float*)carve(N_NODES * 4);
    float*  zs1      = (float*)carve(N_NODES * 4);
    float2* sd       = (float2*)carve((size_t)N_NODES * 8);        // 0.8 MB (L2-resident)
    int*    csr      = (int*)carve((size_t)N_EDGES * 4);           // 12.8 MB
    // 12.8 MB region: ebuf dead after k_bucket; then zs3a(3.2) | zs3b(3.2) | agg3h(6.4)
    char*   region   = (char*)carve((size_t)N_EDGES * 4);
    unsigned*       ebuf  = (unsigned*)region;
    unsigned short* zs3a  = (unsigned short*)region;
    unsigned short* zs3b  = (unsigned short*)(region + (size_t)N_NODES * 16 * 2);
    unsigned short* agg3h = (unsigned short*)(region + (size_t)N_NODES * 32 * 2);

    const int gN    = (N_NODES + NB - 1) / NB;                 // 391
    const int gG2   = (N_NODES + G2_NODES - 1) / G2_NODES;     // 12500
    const int gG3   = (N_NODES * 16 + NB - 1) / NB;            // 6250
    const int gPart = (N_EDGES + PART_TILE - 1) / PART_TILE;   // 782

    k_zero<<<1, NBKT, 0, stream>>>(bhist);
    k_hist<<<1024, NB, 0, stream>>>(dst, bhist);
    k_scan512<<<1, NBKT, 0, stream>>>(bhist, bstart, bcursor);
    k_partition<<<gPart, PART_THREADS, 0, stream>>>(src, dst, bcursor, ebuf);
    k_bucket<<<NBKT, 512, 0, stream>>>(bstart, ebuf, x, rowstart, deg, dinv, zs1, csr);
    k_gather1<<<gN, NB, 0, stream>>>(rowstart, deg, csr, dinv, zs1, sd);
    k_gather2<<<gG2, NB, 0, stream>>>(rowstart, deg, csr, sd,
                                      W1, b1, bn1g, bn1b, bn1m, bn1v,
                                      W2, b2, bn2g, bn2b, bn2m, bn2v, zs3a, zs3b);
    k_gather3h<<<gG3, NB, 0, stream>>>(rowstart, deg, csr, dinv, zs3a, agg3h, 0);
    k_gather3h<<<gG3, NB, 0, stream>>>(rowstart, deg, csr, dinv, zs3b, agg3h, 16);
    k_pool<<<N_GRAPHS, NB, 0, stream>>>(agg3h, batch, W3, b3, out);
}

// Round 12
// 254.711 us; speedup vs baseline: 4.9202x; 1.0415x over previous
//
#include <hip/hip_runtime.h>

#define N_NODES 100000
#define N_EDGES 3200000
#define N_GRAPHS 1024
#define HID 32
#define BN_EPS 1e-5f
#define NB 256

#define NBKT 512
#define NPB 196                 // nodes per bucket; NBKT*NPB = 100352 >= N_NODES
#define PART_TILE 8192
#define PART_THREADS 512
#define PART_EPT (PART_TILE / PART_THREADS)   // 16

#define G2_NODES 8
#define G2_WCAP 1024            // staged edges per window (8 KB LDS; typical span ~264)
#define G2_EPT (G2_WCAP / NB)   // 4 entries per thread

// ---------------- helpers ----------------

__device__ __forceinline__ int lbound(const int* __restrict__ a, int n, int key) {
    int lo = 0, hi = n;
    while (lo < hi) {
        int mid = (lo + hi) >> 1;
        if (a[mid] < key) lo = mid + 1; else hi = mid;
    }
    return lo;
}

__device__ __forceinline__ float bf2f(unsigned short h) {
    return __uint_as_float((unsigned)h << 16);
}
__device__ __forceinline__ unsigned short f2bf(float x) {   // round-to-nearest-even
    unsigned u = __float_as_uint(x);
    u += 0x7fffu + ((u >> 16) & 1u);
    return (unsigned short)(u >> 16);
}

// ---------------- CSR build (bucketed multisplit, 4B-packed edges) ----------------

__global__ void k_zero(int* __restrict__ bhist) {
    bhist[threadIdx.x] = 0;
}

__global__ void k_hist(const int* __restrict__ dst, int* __restrict__ bhist) {
    __shared__ int h[NBKT];
    for (int i = threadIdx.x; i < NBKT; i += NB) h[i] = 0;
    __syncthreads();
    for (int e = blockIdx.x * NB + threadIdx.x; e < N_EDGES; e += gridDim.x * NB)
        atomicAdd(&h[__builtin_nontemporal_load(&dst[e]) / NPB], 1);
    __syncthreads();
    for (int i = threadIdx.x; i < NBKT; i += NB)
        if (h[i]) atomicAdd(&bhist[i], h[i]);
}

// single block of NBKT threads: exclusive scan -> bstart, bcursor
__global__ void k_scan512(const int* __restrict__ bhist, int* __restrict__ bstart,
                          int* __restrict__ bcursor) {
    __shared__ int sm[NBKT];
    int t = threadIdx.x;
    int orig = bhist[t];
    sm[t] = orig;
    __syncthreads();
    for (int off = 1; off < NBKT; off <<= 1) {
        int v = (t >= off) ? sm[t - off] : 0;
        __syncthreads();
        sm[t] += v;
        __syncthreads();
    }
    int ex = sm[t] - orig;
    bstart[t] = ex;
    bcursor[t] = ex;
    if (t == NBKT - 1) bstart[NBKT] = sm[t];
}

// partition edges into bucket-major ebuf; entry = (dst_local << 17) | src  (4B)
// NOTE: plain store for ebuf — scattered 4B writes MUST go through L2 for
// write-combining (R10: NT store here = 110 MB HBM write-through, 112 µs).
__global__ void __launch_bounds__(PART_THREADS) k_partition(
                            const int* __restrict__ src, const int* __restrict__ dst,
                            int* __restrict__ bcursor, unsigned* __restrict__ ebuf) {
    __shared__ int lh[NBKT];
    __shared__ int lcur[NBKT];
    const int tile0 = blockIdx.x * PART_TILE;
    for (int i = threadIdx.x; i < NBKT; i += PART_THREADS) lh[i] = 0;
    __syncthreads();
    int s[PART_EPT], bk[PART_EPT], dl[PART_EPT];
#pragma unroll
    for (int k = 0; k < PART_EPT; ++k) {
        int e = tile0 + k * PART_THREADS + threadIdx.x;
        bool ok = (e < N_EDGES);
        int sv = ok ? __builtin_nontemporal_load(&src[e]) : 0;
        int dv = ok ? __builtin_nontemporal_load(&dst[e]) : 0;
        s[k] = sv;
        bk[k] = ok ? (dv / NPB) : -1;
        dl[k] = dv - bk[k] * NPB;
        if (ok) atomicAdd(&lh[bk[k]], 1);
    }
    __syncthreads();
    for (int i = threadIdx.x; i < NBKT; i += PART_THREADS)
        lcur[i] = lh[i] ? atomicAdd(&bcursor[i], lh[i]) : 0;
    __syncthreads();
#pragma unroll
    for (int k = 0; k < PART_EPT; ++k) {
        if (bk[k] >= 0) {
            int pos = atomicAdd(&lcur[bk[k]], 1);
            ebuf[pos] = ((unsigned)dl[k] << 17) | (unsigned)s[k];
        }
    }
}

// per-bucket: node histogram -> rowstart/deg/dinv/zs1, then scatter csr
__global__ void __launch_bounds__(1024) k_bucket(const int* __restrict__ bstart,
                         const unsigned* __restrict__ ebuf,
                         const float* __restrict__ x,
                         int* __restrict__ rowstart, int* __restrict__ deg,
                         float* __restrict__ dinv, float* __restrict__ zs1,
                         int* __restrict__ csr) {
    __shared__ int hist[NPB];
    __shared__ int sm[256];
    __shared__ int lcur[NPB];
    const int b = blockIdx.x;
    const int node0 = b * NPB;
    const int nn = N_NODES - node0;
    const int elo = bstart[b], ehi = bstart[b + 1];
    const int t = threadIdx.x;

    for (int i = t; i < NPB; i += blockDim.x) hist[i] = 0;
    __syncthreads();
    for (int e = elo + t; e < ehi; e += blockDim.x)
        atomicAdd(&hist[ebuf[e] >> 17], 1);
    __syncthreads();
    int orig = 0;
    if (t < 256) { orig = (t < NPB) ? hist[t] : 0; sm[t] = orig; }
    __syncthreads();
    for (int off = 1; off < 256; off <<= 1) {
        int v = 0;
        if (t < 256 && t >= off) v = sm[t - off];
        __syncthreads();
        if (t < 256) sm[t] += v;
        __syncthreads();
    }
    if (t < NPB) {
        int ex = sm[t] - orig;
        lcur[t] = ex;
        if (t < nn) {
            int node = node0 + t;
            rowstart[node] = elo + ex;
            deg[node] = orig;
            float di = rsqrtf((float)(orig + 1));
            dinv[node] = di;
            zs1[node] = di * x[node];
        }
    }
    __syncthreads();
    for (int e = elo + t; e < ehi; e += blockDim.x) {
        unsigned pk = ebuf[e];
        int pos = atomicAdd(&lcur[pk >> 17], 1);
        csr[elo + pos] = (int)(pk & 0x1FFFFu);
    }
}

// ---------------- layer 1: scalar gather -> sd = (s, dinv) ----------------

__global__ void k_gather1(const int* __restrict__ rowstart, const int* __restrict__ deg,
                          const int* __restrict__ csr, const float* __restrict__ dinv,
                          const float* __restrict__ zs1, float2* __restrict__ sd) {
    int v = blockIdx.x * NB + threadIdx.x;
    if (v < N_NODES) {
        int lo = rowstart[v], n = deg[v];
        float acc = zs1[v];
        int j = 0;
        for (; j + 4 <= n; j += 4) {
            int u0 = __builtin_nontemporal_load(&csr[lo + j]);
            int u1 = __builtin_nontemporal_load(&csr[lo + j + 1]);
            int u2 = __builtin_nontemporal_load(&csr[lo + j + 2]);
            int u3 = __builtin_nontemporal_load(&csr[lo + j + 3]);
            float a0 = zs1[u0], a1 = zs1[u1], a2 = zs1[u2], a3 = zs1[u3];
            acc += (a0 + a1) + (a2 + a3);
        }
        for (; j < n; ++j) acc += zs1[csr[lo + j]];
        float di = dinv[v];
        sd[v] = make_float2(di * acc, di);
    }
}

// ---------------- layer 2: LDS-staged rank-1 gather, async reg prefetch ----------------
// Block = 8 nodes; block's edges contiguous in CSR. Window w+1 is gathered into
// registers while window w is consumed from LDS (T14 async-stage split).
__global__ void k_gather2(const int* __restrict__ rowstart, const int* __restrict__ deg,
                          const int* __restrict__ csr, const float2* __restrict__ sd,
                          const float* __restrict__ W1, const float* __restrict__ b1,
                          const float* __restrict__ g1, const float* __restrict__ bb1,
                          const float* __restrict__ m1, const float* __restrict__ v1,
                          const float* __restrict__ W2,
                          const float* __restrict__ b2, const float* __restrict__ g2,
                          const float* __restrict__ bb2, const float* __restrict__ m2,
                          const float* __restrict__ v2,
                          unsigned short* __restrict__ zs3a,
                          unsigned short* __restrict__ zs3b) {
    __shared__ float Ws[HID * HID];
    __shared__ float2 sde[G2_WCAP];
    __shared__ float rowbuf[G2_NODES][HID + 1];
    __shared__ int sb[2];
    const int tid = threadIdx.x;
    for (int k = tid; k < HID * HID; k += NB) Ws[k] = W2[k];

    const int r = tid >> 5, f = tid & 31;
    const int v = blockIdx.x * G2_NODES + r;
    const bool valid = v < N_NODES;

    if (tid == 0) {
        int first = blockIdx.x * G2_NODES;
        int last = min(first + G2_NODES - 1, N_NODES - 1);
        sb[0] = rowstart[first];
        sb[1] = rowstart[last] + deg[last];
    }

    const float sc1 = g1[f] * rsqrtf(v1[f] + BN_EPS);
    const float A = W1[f] * sc1;
    const float Bc = (b1[f] - m1[f]) * sc1 + bb1[f];

    float di = 0.0f, acc = 0.0f;
    int rs = 0, re = 0;
    if (valid) {
        rs = rowstart[v];
        re = rs + deg[v];
        float2 pv = sd[v];
        di = pv.y;
        acc = di * fmaxf(pv.x * A + Bc, 0.0f);   // self-loop term zs2[v]
    }
    __syncthreads();
    const int blo = sb[0], bhi = sb[1];

    // prologue: gather window 0 into registers
    float2 pre[G2_EPT];
    {
        int wn0 = min(G2_WCAP, bhi - blo);
#pragma unroll
        for (int k = 0; k < G2_EPT; ++k) {
            int i = k * NB + tid;
            pre[k] = (i < wn0)
                ? sd[__builtin_nontemporal_load(&csr[blo + i])]
                : make_float2(0.0f, 0.0f);
        }
    }

    for (int w = blo; w < bhi; w += G2_WCAP) {
        const int wn = min(G2_WCAP, bhi - w);
        // write staged regs -> LDS
#pragma unroll
        for (int k = 0; k < G2_EPT; ++k) {
            int i = k * NB + tid;
            if (i < wn) sde[i] = pre[k];
        }
        // prefetch next window into regs (overlaps with consume below)
        const int wnext = w + G2_WCAP;
        if (wnext < bhi) {
            int wn2 = min(G2_WCAP, bhi - wnext);
#pragma unroll
            for (int k = 0; k < G2_EPT; ++k) {
                int i = k * NB + tid;
                pre[k] = (i < wn2)
                    ? sd[__builtin_nontemporal_load(&csr[wnext + i])]
                    : make_float2(0.0f, 0.0f);
            }
        }
        __syncthreads();
        int jlo = max(rs, w) - w;
        int jhi = min(re, w + wn) - w;
        int j = jlo;
        for (; j + 4 <= jhi; j += 4) {
            float2 p0 = sde[j], p1 = sde[j + 1], p2 = sde[j + 2], p3 = sde[j + 3];
            float a0 = p0.y * fmaxf(p0.x * A + Bc, 0.0f);
            float a1 = p1.y * fmaxf(p1.x * A + Bc, 0.0f);
            float a2 = p2.y * fmaxf(p2.x * A + Bc, 0.0f);
            float a3 = p3.y * fmaxf(p3.x * A + Bc, 0.0f);
            acc += (a0 + a1) + (a2 + a3);
        }
        for (; j < jhi; ++j) {
            float2 p = sde[j];
            acc += p.y * fmaxf(p.x * A + Bc, 0.0f);
        }
        __syncthreads();
    }
    acc *= di;                 // agg2[v,f]
    rowbuf[r][f] = acc;
    __syncthreads();
    if (valid) {
        float h = b2[f];
#pragma unroll
        for (int k = 0; k < HID; ++k) h += rowbuf[r][k] * Ws[k * HID + f];
        float sc2 = g2[f] * rsqrtf(v2[f] + BN_EPS);
        float z = fmaxf((h - m2[f]) * sc2 + bb2[f], 0.0f);
        unsigned short o = f2bf(di * z);
        if (f < 16) zs3a[v * 16 + f] = o;
        else        zs3b[v * 16 + (f - 16)] = o;
    }
}

// ---------------- layer 3: half-feature gather (3.2MB table, L2-resident) ----------------

__global__ void k_gather3h(const int* __restrict__ rowstart, const int* __restrict__ deg,
                           const int* __restrict__ csr, const float* __restrict__ dinv,
                           const unsigned short* __restrict__ tab,   // [N][16]
                           unsigned short* __restrict__ agg3h, int halfofs) {
    int t = blockIdx.x * NB + threadIdx.x;
    int v = t >> 4, f = t & 15;
    if (v < N_NODES) {
        int lo = rowstart[v], n = deg[v];
        float acc = bf2f(tab[v * 16 + f]);
        int j = 0;
        for (; j + 8 <= n; j += 8) {
            int u0 = __builtin_nontemporal_load(&csr[lo + j]);
            int u1 = __builtin_nontemporal_load(&csr[lo + j + 1]);
            int u2 = __builtin_nontemporal_load(&csr[lo + j + 2]);
            int u3 = __builtin_nontemporal_load(&csr[lo + j + 3]);
            int u4 = __builtin_nontemporal_load(&csr[lo + j + 4]);
            int u5 = __builtin_nontemporal_load(&csr[lo + j + 5]);
            int u6 = __builtin_nontemporal_load(&csr[lo + j + 6]);
            int u7 = __builtin_nontemporal_load(&csr[lo + j + 7]);
            float a0 = bf2f(tab[u0 * 16 + f]);
            float a1 = bf2f(tab[u1 * 16 + f]);
            float a2 = bf2f(tab[u2 * 16 + f]);
            float a3 = bf2f(tab[u3 * 16 + f]);
            float a4 = bf2f(tab[u4 * 16 + f]);
            float a5 = bf2f(tab[u5 * 16 + f]);
            float a6 = bf2f(tab[u6 * 16 + f]);
            float a7 = bf2f(tab[u7 * 16 + f]);
            acc += ((a0 + a1) + (a2 + a3)) + ((a4 + a5) + (a6 + a7));
        }
        for (; j < n; ++j) acc += bf2f(tab[csr[lo + j] * 16 + f]);
        __builtin_nontemporal_store(f2bf(dinv[v] * acc), &agg3h[v * HID + halfofs + f]);
    }
}

// ---------------- pool: block per graph, mean then matmul W3 ----------------

__global__ void k_pool(const unsigned short* __restrict__ agg3h,
                       const int* __restrict__ batch,
                       const float* __restrict__ W3, const float* __restrict__ b3,
                       float* __restrict__ out) {
    __shared__ float Ws[HID * HID];
    __shared__ float part[NB / HID][HID + 1];
    __shared__ float mrow[HID];
    int g = blockIdx.x;
    for (int k = threadIdx.x; k < HID * HID; k += NB) Ws[k] = W3[k];

    int lo = lbound(batch, N_NODES, g);
    int hi = lbound(batch, N_NODES, g + 1);

    int r = threadIdx.x >> 5, f = threadIdx.x & 31;
    float acc = 0.0f;
    for (int i = lo + r; i < hi; i += NB / HID)
        acc += bf2f(__builtin_nontemporal_load(&agg3h[i * HID + f]));
    part[r][f] = acc;
    __syncthreads();
    if (threadIdx.x < HID) {
        float srow = 0.0f;
#pragma unroll
        for (int k = 0; k < NB / HID; ++k) srow += part[k][threadIdx.x];
        float c = (float)(hi - lo);
        mrow[threadIdx.x] = (hi > lo) ? srow / c : 0.0f;
    }
    __syncthreads();
    if (threadIdx.x < HID) {
        int ff = threadIdx.x;
        float o = 0.0f;
        if (hi > lo) {
            o = b3[ff];
#pragma unroll
            for (int k = 0; k < HID; ++k) o += mrow[k] * Ws[k * HID + ff];
        }
        out[g * HID + ff] = o;
    }
}

// ---------------- launch ----------------

extern "C" void kernel_launch(void* const* d_in, const int* in_sizes, int n_in,
                              void* d_out, int out_size, void* d_ws, size_t ws_size,
                              hipStream_t stream) {
    const float* x     = (const float*)d_in[0];
    const int*   eidx  = (const int*)d_in[1];     // [2, E]: row0 = src, row1 = dst
    const int*   batch = (const int*)d_in[2];
    const float* W1    = (const float*)d_in[3];
    const float* b1    = (const float*)d_in[4];
    const float* bn1g  = (const float*)d_in[5];
    const float* bn1b  = (const float*)d_in[6];
    const float* bn1m  = (const float*)d_in[7];
    const float* bn1v  = (const float*)d_in[8];
    const float* W2    = (const float*)d_in[9];
    const float* b2    = (const float*)d_in[10];
    const float* bn2g  = (const float*)d_in[11];
    const float* bn2b  = (const float*)d_in[12];
    const float* bn2m  = (const float*)d_in[13];
    const float* bn2v  = (const float*)d_in[14];
    const float* W3    = (const float*)d_in[15];
    const float* b3    = (const float*)d_in[16];
    float* out = (float*)d_out;

    const int* src = eidx;
    const int* dst = eidx + N_EDGES;

    // workspace carving (256B aligned)
    char* ws = (char*)d_ws;
    size_t off = 0;
    auto carve = [&](size_t bytes) {
        void* p = ws + off;
        off += (bytes + 255) & ~size_t(255);
        return p;
    };
    int*    bhist    = (int*)carve(NBKT * 4);
    int*    bstart   = (int*)carve((NBKT + 1) * 4);
    int*    bcursor  = (int*)carve(NBKT * 4);
    int*    rowstart = (int*)carve(N_NODES * 4);
    int*    deg      = (int*)carve(N_NODES * 4);
    float*  dinv     = (float*)carve(N_NODES * 4);
    float*  zs1      = (float*)carve(N_NODES * 4);
    float2* sd       = (float2*)carve((size_t)N_NODES * 8);        // 0.8 MB (L2-resident)
    int*    csr      = (int*)carve((size_t)N_EDGES * 4);           // 12.8 MB
    // 12.8 MB region: ebuf dead after k_bucket; then zs3a(3.2) | zs3b(3.2) | agg3h(6.4)
    char*   region   = (char*)carve((size_t)N_EDGES * 4);
    unsigned*       ebuf  = (unsigned*)region;
    unsigned short* zs3a  = (unsigned short*)region;
    unsigned short* zs3b  = (unsigned short*)(region + (size_t)N_NODES * 16 * 2);
    unsigned short* agg3h = (unsigned short*)(region + (size_t)N_NODES * 32 * 2);

    const int gN    = (N_NODES + NB - 1) / NB;                 // 391
    const int gG2   = (N_NODES + G2_NODES - 1) / G2_NODES;     // 12500
    const int gG3   = (N_NODES * 16 + NB - 1) / NB;            // 6250
    const int gPart = (N_EDGES + PART_TILE - 1) / PART_TILE;   // 391

    k_zero<<<1, NBKT, 0, stream>>>(bhist);
    k_hist<<<1024, NB, 0, stream>>>(dst, bhist);
    k_scan512<<<1, NBKT, 0, stream>>>(bhist, bstart, bcursor);
    k_partition<<<gPart, PART_THREADS, 0, stream>>>(src, dst, bcursor, ebuf);
    k_bucket<<<NBKT, 1024, 0, stream>>>(bstart, ebuf, x, rowstart, deg, dinv, zs1, csr);
    k_gather1<<<gN, NB, 0, stream>>>(rowstart, deg, csr, dinv, zs1, sd);
    k_gather2<<<gG2, NB, 0, stream>>>(rowstart, deg, csr, sd,
                                      W1, b1, bn1g, bn1b, bn1m, bn1v,
                                      W2, b2, bn2g, bn2b, bn2m, bn2v, zs3a, zs3b);
    k_gather3h<<<gG3, NB, 0, stream>>>(rowstart, deg, csr, dinv, zs3a, agg3h, 0);
    k_gather3h<<<gG3, NB, 0, stream>>>(rowstart, deg, csr, dinv, zs3b, agg3h, 16);
    k_pool<<<N_GRAPHS, NB, 0, stream>>>(agg3h, batch, W3, b3, out);
}

// Round 13
// 247.643 us; speedup vs baseline: 5.0606x; 1.0285x over previous
//
#include <hip/hip_runtime.h>

#define N_NODES 100000
#define N_EDGES 3200000
#define N_GRAPHS 1024
#define HID 32
#define BN_EPS 1e-5f
#define NB 256

#define NBKT 512
#define NPB 196                 // nodes per bucket; NBKT*NPB = 100352 >= N_NODES
#define PART_TILE 8192
#define PART_THREADS 512
#define PART_EPT (PART_TILE / PART_THREADS)   // 16

#define G2_NODES 8
#define G2_WCAP 1024            // staged edges per window (8 KB LDS; typical span ~264)
#define G2_EPT (G2_WCAP / NB)   // 4 entries per thread

#define BK_CAP 8192             // LDS-staged ebuf entries per bucket (mean 6250, max ~6600)

// ---------------- helpers ----------------

__device__ __forceinline__ int lbound(const int* __restrict__ a, int n, int key) {
    int lo = 0, hi = n;
    while (lo < hi) {
        int mid = (lo + hi) >> 1;
        if (a[mid] < key) lo = mid + 1; else hi = mid;
    }
    return lo;
}

__device__ __forceinline__ float bf2f(unsigned short h) {
    return __uint_as_float((unsigned)h << 16);
}
__device__ __forceinline__ float bf2f_lo(unsigned w) {
    return __uint_as_float(w << 16);
}
__device__ __forceinline__ float bf2f_hi(unsigned w) {
    return __uint_as_float(w & 0xffff0000u);
}
__device__ __forceinline__ unsigned short f2bf(float x) {   // round-to-nearest-even
    unsigned u = __float_as_uint(x);
    u += 0x7fffu + ((u >> 16) & 1u);
    return (unsigned short)(u >> 16);
}

// ---------------- CSR build (bucketed multisplit, 4B-packed edges) ----------------

__global__ void k_zero(int* __restrict__ bhist) {
    bhist[threadIdx.x] = 0;
}

__global__ void k_hist(const int* __restrict__ dst, int* __restrict__ bhist) {
    __shared__ int h[NBKT];
    for (int i = threadIdx.x; i < NBKT; i += NB) h[i] = 0;
    __syncthreads();
    for (int e = blockIdx.x * NB + threadIdx.x; e < N_EDGES; e += gridDim.x * NB)
        atomicAdd(&h[__builtin_nontemporal_load(&dst[e]) / NPB], 1);
    __syncthreads();
    for (int i = threadIdx.x; i < NBKT; i += NB)
        if (h[i]) atomicAdd(&bhist[i], h[i]);
}

// single block of NBKT threads: exclusive scan -> bstart, bcursor
__global__ void k_scan512(const int* __restrict__ bhist, int* __restrict__ bstart,
                          int* __restrict__ bcursor) {
    __shared__ int sm[NBKT];
    int t = threadIdx.x;
    int orig = bhist[t];
    sm[t] = orig;
    __syncthreads();
    for (int off = 1; off < NBKT; off <<= 1) {
        int v = (t >= off) ? sm[t - off] : 0;
        __syncthreads();
        sm[t] += v;
        __syncthreads();
    }
    int ex = sm[t] - orig;
    bstart[t] = ex;
    bcursor[t] = ex;
    if (t == NBKT - 1) bstart[NBKT] = sm[t];
}

// partition edges into bucket-major ebuf; entry = (dst_local << 17) | src  (4B)
// NOTE: plain store for ebuf — scattered 4B writes MUST go through L2 for
// write-combining (R10: NT store here = 110 MB HBM write-through, 112 µs).
__global__ void __launch_bounds__(PART_THREADS) k_partition(
                            const int* __restrict__ src, const int* __restrict__ dst,
                            int* __restrict__ bcursor, unsigned* __restrict__ ebuf) {
    __shared__ int lh[NBKT];
    __shared__ int lcur[NBKT];
    const int tile0 = blockIdx.x * PART_TILE;
    for (int i = threadIdx.x; i < NBKT; i += PART_THREADS) lh[i] = 0;
    __syncthreads();
    int s[PART_EPT], bk[PART_EPT], dl[PART_EPT];
#pragma unroll
    for (int k = 0; k < PART_EPT; ++k) {
        int e = tile0 + k * PART_THREADS + threadIdx.x;
        bool ok = (e < N_EDGES);
        int sv = ok ? __builtin_nontemporal_load(&src[e]) : 0;
        int dv = ok ? __builtin_nontemporal_load(&dst[e]) : 0;
        s[k] = sv;
        bk[k] = ok ? (dv / NPB) : -1;
        dl[k] = dv - bk[k] * NPB;
        if (ok) atomicAdd(&lh[bk[k]], 1);
    }
    __syncthreads();
    for (int i = threadIdx.x; i < NBKT; i += PART_THREADS)
        lcur[i] = lh[i] ? atomicAdd(&bcursor[i], lh[i]) : 0;
    __syncthreads();
#pragma unroll
    for (int k = 0; k < PART_EPT; ++k) {
        if (bk[k] >= 0) {
            int pos = atomicAdd(&lcur[bk[k]], 1);
            ebuf[pos] = ((unsigned)dl[k] << 17) | (unsigned)s[k];
        }
    }
}

// per-bucket: node histogram -> rowstart/deg/dinv/zs1, then scatter csr.
// ebuf slice staged in LDS during hist pass (saves the 2nd 12.8MB global read).
__global__ void __launch_bounds__(1024) k_bucket(const int* __restrict__ bstart,
                         const unsigned* __restrict__ ebuf,
                         const float* __restrict__ x,
                         int* __restrict__ rowstart, int* __restrict__ deg,
                         float* __restrict__ dinv, float* __restrict__ zs1,
                         int* __restrict__ csr) {
    __shared__ unsigned ebuf_s[BK_CAP];      // 32 KB
    __shared__ int hist[NPB];
    __shared__ int sm[256];
    __shared__ int lcur[NPB];
    const int b = blockIdx.x;
    const int node0 = b * NPB;
    const int nn = N_NODES - node0;
    const int elo = bstart[b], ehi = bstart[b + 1];
    const int t = threadIdx.x;

    for (int i = t; i < NPB; i += blockDim.x) hist[i] = 0;
    __syncthreads();
    for (int e = elo + t; e < ehi; e += blockDim.x) {
        unsigned pk = ebuf[e];
        int idx = e - elo;
        if (idx < BK_CAP) ebuf_s[idx] = pk;
        atomicAdd(&hist[pk >> 17], 1);
    }
    __syncthreads();
    int orig = 0;
    if (t < 256) { orig = (t < NPB) ? hist[t] : 0; sm[t] = orig; }
    __syncthreads();
    for (int off = 1; off < 256; off <<= 1) {
        int v = 0;
        if (t < 256 && t >= off) v = sm[t - off];
        __syncthreads();
        if (t < 256) sm[t] += v;
        __syncthreads();
    }
    if (t < NPB) {
        int ex = sm[t] - orig;
        lcur[t] = ex;
        if (t < nn) {
            int node = node0 + t;
            rowstart[node] = elo + ex;
            deg[node] = orig;
            float di = rsqrtf((float)(orig + 1));
            dinv[node] = di;
            zs1[node] = di * x[node];
        }
    }
    __syncthreads();
    for (int e = elo + t; e < ehi; e += blockDim.x) {
        int idx = e - elo;
        unsigned pk = (idx < BK_CAP) ? ebuf_s[idx] : ebuf[e];
        int pos = atomicAdd(&lcur[pk >> 17], 1);
        csr[elo + pos] = (int)(pk & 0x1FFFFu);
    }
}

// ---------------- layer 1: scalar gather -> sd = (s, dinv) ----------------

__global__ void k_gather1(const int* __restrict__ rowstart, const int* __restrict__ deg,
                          const int* __restrict__ csr, const float* __restrict__ dinv,
                          const float* __restrict__ zs1, float2* __restrict__ sd) {
    int v = blockIdx.x * NB + threadIdx.x;
    if (v < N_NODES) {
        int lo = rowstart[v], n = deg[v];
        float acc = zs1[v];
        int j = 0;
        for (; j + 4 <= n; j += 4) {
            int u0 = __builtin_nontemporal_load(&csr[lo + j]);
            int u1 = __builtin_nontemporal_load(&csr[lo + j + 1]);
            int u2 = __builtin_nontemporal_load(&csr[lo + j + 2]);
            int u3 = __builtin_nontemporal_load(&csr[lo + j + 3]);
            float a0 = zs1[u0], a1 = zs1[u1], a2 = zs1[u2], a3 = zs1[u3];
            acc += (a0 + a1) + (a2 + a3);
        }
        for (; j < n; ++j) acc += zs1[csr[lo + j]];
        float di = dinv[v];
        sd[v] = make_float2(di * acc, di);
    }
}

// ---------------- layer 2: LDS-staged rank-1 gather, async reg prefetch ----------------
// Block = 8 nodes; block's edges contiguous in CSR. Window w+1 is gathered into
// registers while window w is consumed from LDS; consume reads 2 edges per b128.
__global__ void k_gather2(const int* __restrict__ rowstart, const int* __restrict__ deg,
                          const int* __restrict__ csr, const float2* __restrict__ sd,
                          const float* __restrict__ W1, const float* __restrict__ b1,
                          const float* __restrict__ g1, const float* __restrict__ bb1,
                          const float* __restrict__ m1, const float* __restrict__ v1,
                          const float* __restrict__ W2,
                          const float* __restrict__ b2, const float* __restrict__ g2,
                          const float* __restrict__ bb2, const float* __restrict__ m2,
                          const float* __restrict__ v2,
                          unsigned short* __restrict__ zs3a,
                          unsigned short* __restrict__ zs3b) {
    __shared__ float Ws[HID * HID];
    __shared__ float2 sde[G2_WCAP];
    __shared__ float rowbuf[G2_NODES][HID + 1];
    __shared__ int sb[2];
    const int tid = threadIdx.x;
    for (int k = tid; k < HID * HID; k += NB) Ws[k] = W2[k];

    const int r = tid >> 5, f = tid & 31;
    const int v = blockIdx.x * G2_NODES + r;
    const bool valid = v < N_NODES;

    if (tid == 0) {
        int first = blockIdx.x * G2_NODES;
        int last = min(first + G2_NODES - 1, N_NODES - 1);
        sb[0] = rowstart[first];
        sb[1] = rowstart[last] + deg[last];
    }

    const float sc1 = g1[f] * rsqrtf(v1[f] + BN_EPS);
    const float A = W1[f] * sc1;
    const float Bc = (b1[f] - m1[f]) * sc1 + bb1[f];

    float di = 0.0f, acc = 0.0f;
    int rs = 0, re = 0;
    if (valid) {
        rs = rowstart[v];
        re = rs + deg[v];
        float2 pv = sd[v];
        di = pv.y;
        acc = di * fmaxf(pv.x * A + Bc, 0.0f);   // self-loop term zs2[v]
    }
    __syncthreads();
    const int blo = sb[0], bhi = sb[1];

    // prologue: gather window 0 into registers
    float2 pre[G2_EPT];
    {
        int wn0 = min(G2_WCAP, bhi - blo);
#pragma unroll
        for (int k = 0; k < G2_EPT; ++k) {
            int i = k * NB + tid;
            pre[k] = (i < wn0)
                ? sd[__builtin_nontemporal_load(&csr[blo + i])]
                : make_float2(0.0f, 0.0f);
        }
    }

    for (int w = blo; w < bhi; w += G2_WCAP) {
        const int wn = min(G2_WCAP, bhi - w);
        // write staged regs -> LDS
#pragma unroll
        for (int k = 0; k < G2_EPT; ++k) {
            int i = k * NB + tid;
            if (i < wn) sde[i] = pre[k];
        }
        // prefetch next window into regs (overlaps with consume below)
        const int wnext = w + G2_WCAP;
        if (wnext < bhi) {
            int wn2 = min(G2_WCAP, bhi - wnext);
#pragma unroll
            for (int k = 0; k < G2_EPT; ++k) {
                int i = k * NB + tid;
                pre[k] = (i < wn2)
                    ? sd[__builtin_nontemporal_load(&csr[wnext + i])]
                    : make_float2(0.0f, 0.0f);
            }
        }
        __syncthreads();
        int jlo = max(rs, w) - w;
        int jhi = min(re, w + wn) - w;
        int j = jlo;
        if ((j & 1) && j < jhi) {               // align to float4 boundary
            float2 p = sde[j];
            acc += p.y * fmaxf(p.x * A + Bc, 0.0f);
            ++j;
        }
        const float4* sde4 = (const float4*)sde;
        for (; j + 4 <= jhi; j += 4) {
            float4 q0 = sde4[j >> 1];           // sde[j], sde[j+1]
            float4 q1 = sde4[(j >> 1) + 1];     // sde[j+2], sde[j+3]
            float a0 = q0.y * fmaxf(q0.x * A + Bc, 0.0f);
            float a1 = q0.w * fmaxf(q0.z * A + Bc, 0.0f);
            float a2 = q1.y * fmaxf(q1.x * A + Bc, 0.0f);
            float a3 = q1.w * fmaxf(q1.z * A + Bc, 0.0f);
            acc += (a0 + a1) + (a2 + a3);
        }
        for (; j < jhi; ++j) {
            float2 p = sde[j];
            acc += p.y * fmaxf(p.x * A + Bc, 0.0f);
        }
        __syncthreads();
    }
    acc *= di;                 // agg2[v,f]
    rowbuf[r][f] = acc;
    __syncthreads();
    if (valid) {
        float h = b2[f];
#pragma unroll
        for (int k = 0; k < HID; ++k) h += rowbuf[r][k] * Ws[k * HID + f];
        float sc2 = g2[f] * rsqrtf(v2[f] + BN_EPS);
        float z = fmaxf((h - m2[f]) * sc2 + bb2[f], 0.0f);
        unsigned short o = f2bf(di * z);
        if (f < 16) zs3a[v * 16 + f] = o;
        else        zs3b[v * 16 + (f - 16)] = o;
    }
}

// ---------------- layer 3: half-feature gather, 8 lanes/node, uint loads ----------------
// tabu: [N][8] uints (= [N][16] bf16). Lane f2 owns features {2f2, 2f2+1}.

__global__ void k_gather3h(const int* __restrict__ rowstart, const int* __restrict__ deg,
                           const int* __restrict__ csr, const float* __restrict__ dinv,
                           const unsigned* __restrict__ tabu,      // [N][8] uint
                           unsigned* __restrict__ agg3u, int halfuofs) {  // [N][16] uint
    int t = blockIdx.x * NB + threadIdx.x;
    int v = t >> 3, f2 = t & 7;
    if (v < N_NODES) {
        int lo = rowstart[v], n = deg[v];
        unsigned ws = tabu[v * 8 + f2];          // self-loop term
        float a0 = bf2f_lo(ws), a1 = bf2f_hi(ws);
        int j = 0;
        for (; j + 8 <= n; j += 8) {
            int u0 = __builtin_nontemporal_load(&csr[lo + j]);
            int u1 = __builtin_nontemporal_load(&csr[lo + j + 1]);
            int u2 = __builtin_nontemporal_load(&csr[lo + j + 2]);
            int u3 = __builtin_nontemporal_load(&csr[lo + j + 3]);
            int u4 = __builtin_nontemporal_load(&csr[lo + j + 4]);
            int u5 = __builtin_nontemporal_load(&csr[lo + j + 5]);
            int u6 = __builtin_nontemporal_load(&csr[lo + j + 6]);
            int u7 = __builtin_nontemporal_load(&csr[lo + j + 7]);
            unsigned w0 = tabu[u0 * 8 + f2];
            unsigned w1 = tabu[u1 * 8 + f2];
            unsigned w2 = tabu[u2 * 8 + f2];
            unsigned w3 = tabu[u3 * 8 + f2];
            unsigned w4 = tabu[u4 * 8 + f2];
            unsigned w5 = tabu[u5 * 8 + f2];
            unsigned w6 = tabu[u6 * 8 + f2];
            unsigned w7 = tabu[u7 * 8 + f2];
            a0 += ((bf2f_lo(w0) + bf2f_lo(w1)) + (bf2f_lo(w2) + bf2f_lo(w3)))
                + ((bf2f_lo(w4) + bf2f_lo(w5)) + (bf2f_lo(w6) + bf2f_lo(w7)));
            a1 += ((bf2f_hi(w0) + bf2f_hi(w1)) + (bf2f_hi(w2) + bf2f_hi(w3)))
                + ((bf2f_hi(w4) + bf2f_hi(w5)) + (bf2f_hi(w6) + bf2f_hi(w7)));
        }
        for (; j < n; ++j) {
            unsigned w = tabu[__builtin_nontemporal_load(&csr[lo + j]) * 8 + f2];
            a0 += bf2f_lo(w);
            a1 += bf2f_hi(w);
        }
        float di = dinv[v];
        unsigned o = (unsigned)f2bf(di * a0) | ((unsigned)f2bf(di * a1) << 16);
        __builtin_nontemporal_store(o, &agg3u[v * 16 + halfuofs + f2]);
    }
}

// ---------------- pool: block per graph, mean then matmul W3 ----------------

__global__ void k_pool(const unsigned short* __restrict__ agg3h,
                       const int* __restrict__ batch,
                       const float* __restrict__ W3, const float* __restrict__ b3,
                       float* __restrict__ out) {
    __shared__ float Ws[HID * HID];
    __shared__ float part[NB / HID][HID + 1];
    __shared__ float mrow[HID];
    int g = blockIdx.x;
    for (int k = threadIdx.x; k < HID * HID; k += NB) Ws[k] = W3[k];

    int lo = lbound(batch, N_NODES, g);
    int hi = lbound(batch, N_NODES, g + 1);

    int r = threadIdx.x >> 5, f = threadIdx.x & 31;
    float acc = 0.0f;
    for (int i = lo + r; i < hi; i += NB / HID)
        acc += bf2f(__builtin_nontemporal_load(&agg3h[i * HID + f]));
    part[r][f] = acc;
    __syncthreads();
    if (threadIdx.x < HID) {
        float srow = 0.0f;
#pragma unroll
        for (int k = 0; k < NB / HID; ++k) srow += part[k][threadIdx.x];
        float c = (float)(hi - lo);
        mrow[threadIdx.x] = (hi > lo) ? srow / c : 0.0f;
    }
    __syncthreads();
    if (threadIdx.x < HID) {
        int ff = threadIdx.x;
        float o = 0.0f;
        if (hi > lo) {
            o = b3[ff];
#pragma unroll
            for (int k = 0; k < HID; ++k) o += mrow[k] * Ws[k * HID + ff];
        }
        out[g * HID + ff] = o;
    }
}

// ---------------- launch ----------------

extern "C" void kernel_launch(void* const* d_in, const int* in_sizes, int n_in,
                              void* d_out, int out_size, void* d_ws, size_t ws_size,
                              hipStream_t stream) {
    const float* x     = (const float*)d_in[0];
    const int*   eidx  = (const int*)d_in[1];     // [2, E]: row0 = src, row1 = dst
    const int*   batch = (const int*)d_in[2];
    const float* W1    = (const float*)d_in[3];
    const float* b1    = (const float*)d_in[4];
    const float* bn1g  = (const float*)d_in[5];
    const float* bn1b  = (const float*)d_in[6];
    const float* bn1m  = (const float*)d_in[7];
    const float* bn1v  = (const float*)d_in[8];
    const float* W2    = (const float*)d_in[9];
    const float* b2    = (const float*)d_in[10];
    const float* bn2g  = (const float*)d_in[11];
    const float* bn2b  = (const float*)d_in[12];
    const float* bn2m  = (const float*)d_in[13];
    const float* bn2v  = (const float*)d_in[14];
    const float* W3    = (const float*)d_in[15];
    const float* b3    = (const float*)d_in[16];
    float* out = (float*)d_out;

    const int* src = eidx;
    const int* dst = eidx + N_EDGES;

    // workspace carving (256B aligned)
    char* ws = (char*)d_ws;
    size_t off = 0;
    auto carve = [&](size_t bytes) {
        void* p = ws + off;
        off += (bytes + 255) & ~size_t(255);
        return p;
    };
    int*    bhist    = (int*)carve(NBKT * 4);
    int*    bstart   = (int*)carve((NBKT + 1) * 4);
    int*    bcursor  = (int*)carve(NBKT * 4);
    int*    rowstart = (int*)carve(N_NODES * 4);
    int*    deg      = (int*)carve(N_NODES * 4);
    float*  dinv     = (float*)carve(N_NODES * 4);
    float*  zs1      = (float*)carve(N_NODES * 4);
    float2* sd       = (float2*)carve((size_t)N_NODES * 8);        // 0.8 MB (L2-resident)
    int*    csr      = (int*)carve((size_t)N_EDGES * 4);           // 12.8 MB
    // 12.8 MB region: ebuf dead after k_bucket; then zs3a(3.2) | zs3b(3.2) | agg3h(6.4)
    char*   region   = (char*)carve((size_t)N_EDGES * 4);
    unsigned*       ebuf  = (unsigned*)region;
    unsigned short* zs3a  = (unsigned short*)region;
    unsigned short* zs3b  = (unsigned short*)(region + (size_t)N_NODES * 16 * 2);
    unsigned short* agg3h = (unsigned short*)(region + (size_t)N_NODES * 32 * 2);
    unsigned*       agg3u = (unsigned*)agg3h;

    const int gN    = (N_NODES + NB - 1) / NB;                 // 391
    const int gG2   = (N_NODES + G2_NODES - 1) / G2_NODES;     // 12500
    const int gG3   = (N_NODES * 8 + NB - 1) / NB;             // 3125
    const int gPart = (N_EDGES + PART_TILE - 1) / PART_TILE;   // 391

    k_zero<<<1, NBKT, 0, stream>>>(bhist);
    k_hist<<<1024, NB, 0, stream>>>(dst, bhist);
    k_scan512<<<1, NBKT, 0, stream>>>(bhist, bstart, bcursor);
    k_partition<<<gPart, PART_THREADS, 0, stream>>>(src, dst, bcursor, ebuf);
    k_bucket<<<NBKT, 1024, 0, stream>>>(bstart, ebuf, x, rowstart, deg, dinv, zs1, csr);
    k_gather1<<<gN, NB, 0, stream>>>(rowstart, deg, csr, dinv, zs1, sd);
    k_gather2<<<gG2, NB, 0, stream>>>(rowstart, deg, csr, sd,
                                      W1, b1, bn1g, bn1b, bn1m, bn1v,
                                      W2, b2, bn2g, bn2b, bn2m, bn2v, zs3a, zs3b);
    k_gather3h<<<gG3, NB, 0, stream>>>(rowstart, deg, csr, dinv,
                                       (const unsigned*)zs3a, agg3u, 0);
    k_gather3h<<<gG3, NB, 0, stream>>>(rowstart, deg, csr, dinv,
                                       (const unsigned*)zs3b, agg3u, 8);
    k_pool<<<N_GRAPHS, NB, 0, stream>>>(agg3h, batch, W3, b3, out);
}

// Round 15
// 240.437 us; speedup vs baseline: 5.2123x; 1.0300x over previous
//
#include <hip/hip_runtime.h>

#define N_NODES 100000
#define N_EDGES 3200000
#define N_GRAPHS 1024
#define HID 32
#define BN_EPS 1e-5f
#define NB 256

#define NBKT 512
#define NPB 196                 // nodes per bucket; NBKT*NPB = 100352 >= N_NODES
#define PART_TILE 8192
#define PART_THREADS 512
#define PART_EPT (PART_TILE / PART_THREADS)   // 16 (divides N_EDGES)

#define G2_NODES 16
#define G2_THREADS 512
#define G2_WCAP 1024            // staged edges per window (8 KB LDS; typical span ~512)
#define G2_EPT (G2_WCAP / G2_THREADS)   // 2

#define BK_CAP 8192             // LDS-staged ebuf entries per bucket (mean 6250, max ~6600)

typedef int vint4 __attribute__((ext_vector_type(4)));   // NT-load-compatible int4

// ---------------- helpers ----------------

__device__ __forceinline__ int lbound(const int* __restrict__ a, int n, int key) {
    int lo = 0, hi = n;
    while (lo < hi) {
        int mid = (lo + hi) >> 1;
        if (a[mid] < key) lo = mid + 1; else hi = mid;
    }
    return lo;
}

__device__ __forceinline__ float bf2f(unsigned short h) {
    return __uint_as_float((unsigned)h << 16);
}
__device__ __forceinline__ float bf2f_lo(unsigned w) {
    return __uint_as_float(w << 16);
}
__device__ __forceinline__ float bf2f_hi(unsigned w) {
    return __uint_as_float(w & 0xffff0000u);
}
__device__ __forceinline__ unsigned short f2bf(float x) {   // round-to-nearest-even
    unsigned u = __float_as_uint(x);
    u += 0x7fffu + ((u >> 16) & 1u);
    return (unsigned short)(u >> 16);
}

// ---------------- CSR build (bucketed multisplit, 4B-packed edges) ----------------

__global__ void k_zero(int* __restrict__ bhist) {
    bhist[threadIdx.x] = 0;
}

__global__ void k_hist(const int* __restrict__ dst, int* __restrict__ bhist) {
    __shared__ int h[NBKT];
    for (int i = threadIdx.x; i < NBKT; i += NB) h[i] = 0;
    __syncthreads();
    const vint4* d4 = (const vint4*)dst;
    const int nq = N_EDGES / 4;
    for (int q = blockIdx.x * NB + threadIdx.x; q < nq; q += gridDim.x * NB) {
        vint4 d = __builtin_nontemporal_load(&d4[q]);
        atomicAdd(&h[d.x / NPB], 1);
        atomicAdd(&h[d.y / NPB], 1);
        atomicAdd(&h[d.z / NPB], 1);
        atomicAdd(&h[d.w / NPB], 1);
    }
    __syncthreads();
    for (int i = threadIdx.x; i < NBKT; i += NB)
        if (h[i]) atomicAdd(&bhist[i], h[i]);
}

// single block of NBKT threads: exclusive scan -> bstart, bcursor
__global__ void k_scan512(const int* __restrict__ bhist, int* __restrict__ bstart,
                          int* __restrict__ bcursor) {
    __shared__ int sm[NBKT];
    int t = threadIdx.x;
    int orig = bhist[t];
    sm[t] = orig;
    __syncthreads();
    for (int off = 1; off < NBKT; off <<= 1) {
        int v = (t >= off) ? sm[t - off] : 0;
        __syncthreads();
        sm[t] += v;
        __syncthreads();
    }
    int ex = sm[t] - orig;
    bstart[t] = ex;
    bcursor[t] = ex;
    if (t == NBKT - 1) bstart[NBKT] = sm[t];
}

// partition edges into bucket-major ebuf; entry = (dst_local << 17) | src  (4B)
// Per-thread-contiguous vint4 loads (N_EDGES % 16 == 0 -> all-or-nothing guard).
// NOTE: plain store for ebuf — scattered 4B writes MUST go through L2 for
// write-combining (R10: NT store here = 110 MB HBM write-through, 112 µs).
__global__ void __launch_bounds__(PART_THREADS) k_partition(
                            const int* __restrict__ src, const int* __restrict__ dst,
                            int* __restrict__ bcursor, unsigned* __restrict__ ebuf) {
    __shared__ int lh[NBKT];
    __shared__ int lcur[NBKT];
    const int ebase = blockIdx.x * PART_TILE + threadIdx.x * PART_EPT;
    const bool ok = ebase < N_EDGES;
    for (int i = threadIdx.x; i < NBKT; i += PART_THREADS) lh[i] = 0;
    __syncthreads();
    int s[PART_EPT], bk[PART_EPT], dl[PART_EPT];
    if (ok) {
        const vint4* s4 = (const vint4*)(src + ebase);
        const vint4* d4 = (const vint4*)(dst + ebase);
#pragma unroll
        for (int q = 0; q < PART_EPT / 4; ++q) {
            vint4 sv = __builtin_nontemporal_load(&s4[q]);
            vint4 dv = __builtin_nontemporal_load(&d4[q]);
            int svv[4] = {sv.x, sv.y, sv.z, sv.w};
            int dvv[4] = {dv.x, dv.y, dv.z, dv.w};
#pragma unroll
            for (int r = 0; r < 4; ++r) {
                int k = q * 4 + r;
                s[k] = svv[r];
                bk[k] = dvv[r] / NPB;
                dl[k] = dvv[r] - bk[k] * NPB;
                atomicAdd(&lh[bk[k]], 1);
            }
        }
    }
    __syncthreads();
    for (int i = threadIdx.x; i < NBKT; i += PART_THREADS)
        lcur[i] = lh[i] ? atomicAdd(&bcursor[i], lh[i]) : 0;
    __syncthreads();
    if (ok) {
#pragma unroll
        for (int k = 0; k < PART_EPT; ++k) {
            int pos = atomicAdd(&lcur[bk[k]], 1);
            ebuf[pos] = ((unsigned)dl[k] << 17) | (unsigned)s[k];
        }
    }
}

// per-bucket: node histogram -> rowstart/deg/dinv/zs1, then scatter csr.
// ebuf slice staged in LDS during hist pass (saves the 2nd 12.8MB global read).
__global__ void __launch_bounds__(1024) k_bucket(const int* __restrict__ bstart,
                         const unsigned* __restrict__ ebuf,
                         const float* __restrict__ x,
                         int* __restrict__ rowstart, int* __restrict__ deg,
                         float* __restrict__ dinv, float* __restrict__ zs1,
                         int* __restrict__ csr) {
    __shared__ unsigned ebuf_s[BK_CAP];      // 32 KB
    __shared__ int hist[NPB];
    __shared__ int sm[256];
    __shared__ int lcur[NPB];
    const int b = blockIdx.x;
    const int node0 = b * NPB;
    const int nn = N_NODES - node0;
    const int elo = bstart[b], ehi = bstart[b + 1];
    const int t = threadIdx.x;

    for (int i = t; i < NPB; i += blockDim.x) hist[i] = 0;
    __syncthreads();
    for (int e = elo + t; e < ehi; e += blockDim.x) {
        unsigned pk = ebuf[e];
        int idx = e - elo;
        if (idx < BK_CAP) ebuf_s[idx] = pk;
        atomicAdd(&hist[pk >> 17], 1);
    }
    __syncthreads();
    int orig = 0;
    if (t < 256) { orig = (t < NPB) ? hist[t] : 0; sm[t] = orig; }
    __syncthreads();
    for (int off = 1; off < 256; off <<= 1) {
        int v = 0;
        if (t < 256 && t >= off) v = sm[t - off];
        __syncthreads();
        if (t < 256) sm[t] += v;
        __syncthreads();
    }
    if (t < NPB) {
        int ex = sm[t] - orig;
        lcur[t] = ex;
        if (t < nn) {
            int node = node0 + t;
            rowstart[node] = elo + ex;
            deg[node] = orig;
            float di = rsqrtf((float)(orig + 1));
            dinv[node] = di;
            zs1[node] = di * x[node];
        }
    }
    __syncthreads();
    for (int e = elo + t; e < ehi; e += blockDim.x) {
        int idx = e - elo;
        unsigned pk = (idx < BK_CAP) ? ebuf_s[idx] : ebuf[e];
        int pos = atomicAdd(&lcur[pk >> 17], 1);
        csr[elo + pos] = (int)(pk & 0x1FFFFu);
    }
}

// ---------------- layer 1: scalar gather -> sd = (s, dinv) ----------------

__global__ void k_gather1(const int* __restrict__ rowstart, const int* __restrict__ deg,
                          const int* __restrict__ csr, const float* __restrict__ dinv,
                          const float* __restrict__ zs1, float2* __restrict__ sd) {
    int v = blockIdx.x * NB + threadIdx.x;
    if (v < N_NODES) {
        int lo = rowstart[v], n = deg[v];
        float acc = zs1[v];
        int j = 0;
        for (; j + 4 <= n; j += 4) {
            int u0 = __builtin_nontemporal_load(&csr[lo + j]);
            int u1 = __builtin_nontemporal_load(&csr[lo + j + 1]);
            int u2 = __builtin_nontemporal_load(&csr[lo + j + 2]);
            int u3 = __builtin_nontemporal_load(&csr[lo + j + 3]);
            float a0 = zs1[u0], a1 = zs1[u1], a2 = zs1[u2], a3 = zs1[u3];
            acc += (a0 + a1) + (a2 + a3);
        }
        for (; j < n; ++j) acc += zs1[csr[lo + j]];
        float di = dinv[v];
        sd[v] = make_float2(di * acc, di);
    }
}

// ---------------- layer 2: LDS-staged rank-1 gather, async reg prefetch ----------------
// Block = 16 nodes (512 thr); block's edges contiguous in CSR. Window w+1 gathered
// into registers while window w is consumed from LDS; consume reads 2 edges per b128.
__global__ void __launch_bounds__(G2_THREADS) k_gather2(
                          const int* __restrict__ rowstart, const int* __restrict__ deg,
                          const int* __restrict__ csr, const float2* __restrict__ sd,
                          const float* __restrict__ W1, const float* __restrict__ b1,
                          const float* __restrict__ g1, const float* __restrict__ bb1,
                          const float* __restrict__ m1, const float* __restrict__ v1,
                          const float* __restrict__ W2,
                          const float* __restrict__ b2, const float* __restrict__ g2,
                          const float* __restrict__ bb2, const float* __restrict__ m2,
                          const float* __restrict__ v2,
                          unsigned short* __restrict__ zs3a,
                          unsigned short* __restrict__ zs3b) {
    __shared__ float Ws[HID * HID];
    __shared__ float2 sde[G2_WCAP];
    __shared__ float rowbuf[G2_NODES][HID + 1];
    __shared__ int sb[2];
    const int tid = threadIdx.x;
    for (int k = tid; k < HID * HID; k += G2_THREADS) Ws[k] = W2[k];

    const int r = tid >> 5, f = tid & 31;
    const int v = blockIdx.x * G2_NODES + r;
    const bool valid = v < N_NODES;

    if (tid == 0) {
        int first = blockIdx.x * G2_NODES;
        int last = min(first + G2_NODES - 1, N_NODES - 1);
        sb[0] = rowstart[first];
        sb[1] = rowstart[last] + deg[last];
    }

    const float sc1 = g1[f] * rsqrtf(v1[f] + BN_EPS);
    const float A = W1[f] * sc1;
    const float Bc = (b1[f] - m1[f]) * sc1 + bb1[f];

    float di = 0.0f, acc = 0.0f;
    int rs = 0, re = 0;
    if (valid) {
        rs = rowstart[v];
        re = rs + deg[v];
        float2 pv = sd[v];
        di = pv.y;
        acc = di * fmaxf(pv.x * A + Bc, 0.0f);   // self-loop term zs2[v]
    }
    __syncthreads();
    const int blo = sb[0], bhi = sb[1];

    // prologue: gather window 0 into registers
    float2 pre[G2_EPT];
    {
        int wn0 = min(G2_WCAP, bhi - blo);
#pragma unroll
        for (int k = 0; k < G2_EPT; ++k) {
            int i = k * G2_THREADS + tid;
            pre[k] = (i < wn0)
                ? sd[__builtin_nontemporal_load(&csr[blo + i])]
                : make_float2(0.0f, 0.0f);
        }
    }

    for (int w = blo; w < bhi; w += G2_WCAP) {
        const int wn = min(G2_WCAP, bhi - w);
        // write staged regs -> LDS
#pragma unroll
        for (int k = 0; k < G2_EPT; ++k) {
            int i = k * G2_THREADS + tid;
            if (i < wn) sde[i] = pre[k];
        }
        // prefetch next window into regs (overlaps with consume below)
        const int wnext = w + G2_WCAP;
        if (wnext < bhi) {
            int wn2 = min(G2_WCAP, bhi - wnext);
#pragma unroll
            for (int k = 0; k < G2_EPT; ++k) {
                int i = k * G2_THREADS + tid;
                pre[k] = (i < wn2)
                    ? sd[__builtin_nontemporal_load(&csr[wnext + i])]
                    : make_float2(0.0f, 0.0f);
            }
        }
        __syncthreads();
        int jlo = max(rs, w) - w;
        int jhi = min(re, w + wn) - w;
        int j = jlo;
        if ((j & 1) && j < jhi) {               // align to float4 boundary
            float2 p = sde[j];
            acc += p.y * fmaxf(p.x * A + Bc, 0.0f);
            ++j;
        }
        const float4* sde4 = (const float4*)sde;
        for (; j + 4 <= jhi; j += 4) {
            float4 q0 = sde4[j >> 1];           // sde[j], sde[j+1]
            float4 q1 = sde4[(j >> 1) + 1];     // sde[j+2], sde[j+3]
            float a0 = q0.y * fmaxf(q0.x * A + Bc, 0.0f);
            float a1 = q0.w * fmaxf(q0.z * A + Bc, 0.0f);
            float a2 = q1.y * fmaxf(q1.x * A + Bc, 0.0f);
            float a3 = q1.w * fmaxf(q1.z * A + Bc, 0.0f);
            acc += (a0 + a1) + (a2 + a3);
        }
        for (; j < jhi; ++j) {
            float2 p = sde[j];
            acc += p.y * fmaxf(p.x * A + Bc, 0.0f);
        }
        __syncthreads();
    }
    acc *= di;                 // agg2[v,f]
    rowbuf[r][f] = acc;
    __syncthreads();
    if (valid) {
        float h = b2[f];
#pragma unroll
        for (int k = 0; k < HID; ++k) h += rowbuf[r][k] * Ws[k * HID + f];
        float sc2 = g2[f] * rsqrtf(v2[f] + BN_EPS);
        float z = fmaxf((h - m2[f]) * sc2 + bb2[f], 0.0f);
        unsigned short o = f2bf(di * z);
        if (f < 16) zs3a[v * 16 + f] = o;
        else        zs3b[v * 16 + (f - 16)] = o;
    }
}

// ---------------- layer 3: half-feature gather, 8 lanes/node, uint loads ----------------
// tabu: [N][8] uints (= [N][16] bf16). Lane f2 owns features {2f2, 2f2+1}.

__global__ void k_gather3h(const int* __restrict__ rowstart, const int* __restrict__ deg,
                           const int* __restrict__ csr, const float* __restrict__ dinv,
                           const unsigned* __restrict__ tabu,      // [N][8] uint
                           unsigned* __restrict__ agg3u, int halfuofs) {  // [N][16] uint
    int t = blockIdx.x * NB + threadIdx.x;
    int v = t >> 3, f2 = t & 7;
    if (v < N_NODES) {
        int lo = rowstart[v], n = deg[v];
        unsigned ws = tabu[v * 8 + f2];          // self-loop term
        float a0 = bf2f_lo(ws), a1 = bf2f_hi(ws);
        int j = 0;
        for (; j + 8 <= n; j += 8) {
            int u0 = __builtin_nontemporal_load(&csr[lo + j]);
            int u1 = __builtin_nontemporal_load(&csr[lo + j + 1]);
            int u2 = __builtin_nontemporal_load(&csr[lo + j + 2]);
            int u3 = __builtin_nontemporal_load(&csr[lo + j + 3]);
            int u4 = __builtin_nontemporal_load(&csr[lo + j + 4]);
            int u5 = __builtin_nontemporal_load(&csr[lo + j + 5]);
            int u6 = __builtin_nontemporal_load(&csr[lo + j + 6]);
            int u7 = __builtin_nontemporal_load(&csr[lo + j + 7]);
            unsigned w0 = tabu[u0 * 8 + f2];
            unsigned w1 = tabu[u1 * 8 + f2];
            unsigned w2 = tabu[u2 * 8 + f2];
            unsigned w3 = tabu[u3 * 8 + f2];
            unsigned w4 = tabu[u4 * 8 + f2];
            unsigned w5 = tabu[u5 * 8 + f2];
            unsigned w6 = tabu[u6 * 8 + f2];
            unsigned w7 = tabu[u7 * 8 + f2];
            a0 += ((bf2f_lo(w0) + bf2f_lo(w1)) + (bf2f_lo(w2) + bf2f_lo(w3)))
                + ((bf2f_lo(w4) + bf2f_lo(w5)) + (bf2f_lo(w6) + bf2f_lo(w7)));
            a1 += ((bf2f_hi(w0) + bf2f_hi(w1)) + (bf2f_hi(w2) + bf2f_hi(w3)))
                + ((bf2f_hi(w4) + bf2f_hi(w5)) + (bf2f_hi(w6) + bf2f_hi(w7)));
        }
        for (; j < n; ++j) {
            unsigned w = tabu[__builtin_nontemporal_load(&csr[lo + j]) * 8 + f2];
            a0 += bf2f_lo(w);
            a1 += bf2f_hi(w);
        }
        float di = dinv[v];
        unsigned o = (unsigned)f2bf(di * a0) | ((unsigned)f2bf(di * a1) << 16);
        __builtin_nontemporal_store(o, &agg3u[v * 16 + halfuofs + f2]);
    }
}

// ---------------- pool: block per graph, mean then matmul W3 ----------------

__global__ void k_pool(const unsigned short* __restrict__ agg3h,
                       const int* __restrict__ batch,
                       const float* __restrict__ W3, const float* __restrict__ b3,
                       float* __restrict__ out) {
    __shared__ float Ws[HID * HID];
    __shared__ float part[NB / HID][HID + 1];
    __shared__ float mrow[HID];
    int g = blockIdx.x;
    for (int k = threadIdx.x; k < HID * HID; k += NB) Ws[k] = W3[k];

    int lo = lbound(batch, N_NODES, g);
    int hi = lbound(batch, N_NODES, g + 1);

    int r = threadIdx.x >> 5, f = threadIdx.x & 31;
    float acc = 0.0f;
    for (int i = lo + r; i < hi; i += NB / HID)
        acc += bf2f(__builtin_nontemporal_load(&agg3h[i * HID + f]));
    part[r][f] = acc;
    __syncthreads();
    if (threadIdx.x < HID) {
        float srow = 0.0f;
#pragma unroll
        for (int k = 0; k < NB / HID; ++k) srow += part[k][threadIdx.x];
        float c = (float)(hi - lo);
        mrow[threadIdx.x] = (hi > lo) ? srow / c : 0.0f;
    }
    __syncthreads();
    if (threadIdx.x < HID) {
        int ff = threadIdx.x;
        float o = 0.0f;
        if (hi > lo) {
            o = b3[ff];
#pragma unroll
            for (int k = 0; k < HID; ++k) o += mrow[k] * Ws[k * HID + ff];
        }
        out[g * HID + ff] = o;
    }
}

// ---------------- launch ----------------

extern "C" void kernel_launch(void* const* d_in, const int* in_sizes, int n_in,
                              void* d_out, int out_size, void* d_ws, size_t ws_size,
                              hipStream_t stream) {
    const float* x     = (const float*)d_in[0];
    const int*   eidx  = (const int*)d_in[1];     // [2, E]: row0 = src, row1 = dst
    const int*   batch = (const int*)d_in[2];
    const float* W1    = (const float*)d_in[3];
    const float* b1    = (const float*)d_in[4];
    const float* bn1g  = (const float*)d_in[5];
    const float* bn1b  = (const float*)d_in[6];
    const float* bn1m  = (const float*)d_in[7];
    const float* bn1v  = (const float*)d_in[8];
    const float* W2    = (const float*)d_in[9];
    const float* b2    = (const float*)d_in[10];
    const float* bn2g  = (const float*)d_in[11];
    const float* bn2b  = (const float*)d_in[12];
    const float* bn2m  = (const float*)d_in[13];
    const float* bn2v  = (const float*)d_in[14];
    const float* W3    = (const float*)d_in[15];
    const float* b3    = (const float*)d_in[16];
    float* out = (float*)d_out;

    const int* src = eidx;
    const int* dst = eidx + N_EDGES;

    // workspace carving (256B aligned)
    char* ws = (char*)d_ws;
    size_t off = 0;
    auto carve = [&](size_t bytes) {
        void* p = ws + off;
        off += (bytes + 255) & ~size_t(255);
        return p;
    };
    int*    bhist    = (int*)carve(NBKT * 4);
    int*    bstart   = (int*)carve((NBKT + 1) * 4);
    int*    bcursor  = (int*)carve(NBKT * 4);
    int*    rowstart = (int*)carve(N_NODES * 4);
    int*    deg      = (int*)carve(N_NODES * 4);
    float*  dinv     = (float*)carve(N_NODES * 4);
    float*  zs1      = (float*)carve(N_NODES * 4);
    float2* sd       = (float2*)carve((size_t)N_NODES * 8);        // 0.8 MB (L2-resident)
    int*    csr      = (int*)carve((size_t)N_EDGES * 4);           // 12.8 MB
    // 12.8 MB region: ebuf dead after k_bucket; then zs3a(3.2) | zs3b(3.2) | agg3h(6.4)
    char*   region   = (char*)carve((size_t)N_EDGES * 4);
    unsigned*       ebuf  = (unsigned*)region;
    unsigned short* zs3a  = (unsigned short*)region;
    unsigned short* zs3b  = (unsigned short*)(region + (size_t)N_NODES * 16 * 2);
    unsigned short* agg3h = (unsigned short*)(region + (size_t)N_NODES * 32 * 2);
    unsigned*       agg3u = (unsigned*)agg3h;

    const int gN    = (N_NODES + NB - 1) / NB;                 // 391
    const int gG2   = (N_NODES + G2_NODES - 1) / G2_NODES;     // 6250
    const int gG3   = (N_NODES * 8 + NB - 1) / NB;             // 3125
    const int gPart = (N_EDGES + PART_TILE - 1) / PART_TILE;   // 391

    k_zero<<<1, NBKT, 0, stream>>>(bhist);
    k_hist<<<1024, NB, 0, stream>>>(dst, bhist);
    k_scan512<<<1, NBKT, 0, stream>>>(bhist, bstart, bcursor);
    k_partition<<<gPart, PART_THREADS, 0, stream>>>(src, dst, bcursor, ebuf);
    k_bucket<<<NBKT, 1024, 0, stream>>>(bstart, ebuf, x, rowstart, deg, dinv, zs1, csr);
    k_gather1<<<gN, NB, 0, stream>>>(rowstart, deg, csr, dinv, zs1, sd);
    k_gather2<<<gG2, G2_THREADS, 0, stream>>>(rowstart, deg, csr, sd,
                                      W1, b1, bn1g, bn1b, bn1m, bn1v,
                                      W2, b2, bn2g, bn2b, bn2m, bn2v, zs3a, zs3b);
    k_gather3h<<<gG3, NB, 0, stream>>>(rowstart, deg, csr, dinv,
                                       (const unsigned*)zs3a, agg3u, 0);
    k_gather3h<<<gG3, NB, 0, stream>>>(rowstart, deg, csr, dinv,
                                       (const unsigned*)zs3b, agg3u, 8);
    k_pool<<<N_GRAPHS, NB, 0, stream>>>(agg3h, batch, W3, b3, out);
}

// Round 16
// 239.399 us; speedup vs baseline: 5.2349x; 1.0043x over previous
//
#include <hip/hip_runtime.h>

#define N_NODES 100000
#define N_EDGES 3200000
#define N_GRAPHS 1024
#define HID 32
#define BN_EPS 1e-5f
#define NB 256

#define NBKT 512
#define NPB 196                 // nodes per bucket; NBKT*NPB = 100352 >= N_NODES
#define PART_TILE 8192
#define PART_THREADS 512
#define PART_EPT (PART_TILE / PART_THREADS)   // 16 (divides N_EDGES)

#define G2_NODES 16
#define G2_THREADS 512
#define G2_WCAP 1024            // staged edges per window (8 KB LDS; typical span ~512)
#define G2_EPT (G2_WCAP / G2_THREADS)   // 2

#define BK_CAP 8192             // LDS-staged ebuf entries per bucket (mean 6250, max ~6600)

typedef int vint4 __attribute__((ext_vector_type(4)));   // NT-load-compatible int4

// ---------------- helpers ----------------

__device__ __forceinline__ int lbound(const int* __restrict__ a, int n, int key) {
    int lo = 0, hi = n;
    while (lo < hi) {
        int mid = (lo + hi) >> 1;
        if (a[mid] < key) lo = mid + 1; else hi = mid;
    }
    return lo;
}

__device__ __forceinline__ float bf2f(unsigned short h) {
    return __uint_as_float((unsigned)h << 16);
}
__device__ __forceinline__ float bf2f_lo(unsigned w) {
    return __uint_as_float(w << 16);
}
__device__ __forceinline__ float bf2f_hi(unsigned w) {
    return __uint_as_float(w & 0xffff0000u);
}
__device__ __forceinline__ unsigned short f2bf(float x) {   // round-to-nearest-even
    unsigned u = __float_as_uint(x);
    u += 0x7fffu + ((u >> 16) & 1u);
    return (unsigned short)(u >> 16);
}

// ---------------- CSR build (bucketed multisplit, 4B-packed edges) ----------------

__global__ void k_zero(int* __restrict__ bhist) {
    bhist[threadIdx.x] = 0;
}

__global__ void k_hist(const int* __restrict__ dst, int* __restrict__ bhist) {
    __shared__ int h[NBKT];
    for (int i = threadIdx.x; i < NBKT; i += NB) h[i] = 0;
    __syncthreads();
    const vint4* d4 = (const vint4*)dst;
    const int nq = N_EDGES / 4;
    for (int q = blockIdx.x * NB + threadIdx.x; q < nq; q += gridDim.x * NB) {
        vint4 d = __builtin_nontemporal_load(&d4[q]);
        atomicAdd(&h[d.x / NPB], 1);
        atomicAdd(&h[d.y / NPB], 1);
        atomicAdd(&h[d.z / NPB], 1);
        atomicAdd(&h[d.w / NPB], 1);
    }
    __syncthreads();
    for (int i = threadIdx.x; i < NBKT; i += NB)
        if (h[i]) atomicAdd(&bhist[i], h[i]);
}

// single block of NBKT threads: exclusive scan -> bstart, bcursor
__global__ void k_scan512(const int* __restrict__ bhist, int* __restrict__ bstart,
                          int* __restrict__ bcursor) {
    __shared__ int sm[NBKT];
    int t = threadIdx.x;
    int orig = bhist[t];
    sm[t] = orig;
    __syncthreads();
    for (int off = 1; off < NBKT; off <<= 1) {
        int v = (t >= off) ? sm[t - off] : 0;
        __syncthreads();
        sm[t] += v;
        __syncthreads();
    }
    int ex = sm[t] - orig;
    bstart[t] = ex;
    bcursor[t] = ex;
    if (t == NBKT - 1) bstart[NBKT] = sm[t];
}

// partition edges into bucket-major ebuf; entry = (dst_local << 17) | src  (4B)
// Per-thread-contiguous vint4 loads (N_EDGES % 16 == 0 -> all-or-nothing guard).
// NOTE: plain store for ebuf — scattered 4B writes MUST go through L2 for
// write-combining (R10: NT store here = 110 MB HBM write-through, 112 µs).
__global__ void __launch_bounds__(PART_THREADS) k_partition(
                            const int* __restrict__ src, const int* __restrict__ dst,
                            int* __restrict__ bcursor, unsigned* __restrict__ ebuf) {
    __shared__ int lh[NBKT];
    __shared__ int lcur[NBKT];
    const int ebase = blockIdx.x * PART_TILE + threadIdx.x * PART_EPT;
    const bool ok = ebase < N_EDGES;
    for (int i = threadIdx.x; i < NBKT; i += PART_THREADS) lh[i] = 0;
    __syncthreads();
    int s[PART_EPT], bk[PART_EPT], dl[PART_EPT];
    if (ok) {
        const vint4* s4 = (const vint4*)(src + ebase);
        const vint4* d4 = (const vint4*)(dst + ebase);
#pragma unroll
        for (int q = 0; q < PART_EPT / 4; ++q) {
            vint4 sv = __builtin_nontemporal_load(&s4[q]);
            vint4 dv = __builtin_nontemporal_load(&d4[q]);
            int svv[4] = {sv.x, sv.y, sv.z, sv.w};
            int dvv[4] = {dv.x, dv.y, dv.z, dv.w};
#pragma unroll
            for (int r = 0; r < 4; ++r) {
                int k = q * 4 + r;
                s[k] = svv[r];
                bk[k] = dvv[r] / NPB;
                dl[k] = dvv[r] - bk[k] * NPB;
                atomicAdd(&lh[bk[k]], 1);
            }
        }
    }
    __syncthreads();
    for (int i = threadIdx.x; i < NBKT; i += PART_THREADS)
        lcur[i] = lh[i] ? atomicAdd(&bcursor[i], lh[i]) : 0;
    __syncthreads();
    if (ok) {
#pragma unroll
        for (int k = 0; k < PART_EPT; ++k) {
            int pos = atomicAdd(&lcur[bk[k]], 1);
            ebuf[pos] = ((unsigned)dl[k] << 17) | (unsigned)s[k];
        }
    }
}

// per-bucket: node histogram -> rowstart/deg/dinv/zs1, then scatter csr.
// ebuf slice staged in LDS during hist pass (saves the 2nd 12.8MB global read);
// pass-1 reads ebuf as aligned vint4 (4 edges/load inst).
__global__ void __launch_bounds__(1024) k_bucket(const int* __restrict__ bstart,
                         const unsigned* __restrict__ ebuf,
                         const float* __restrict__ x,
                         int* __restrict__ rowstart, int* __restrict__ deg,
                         float* __restrict__ dinv, float* __restrict__ zs1,
                         int* __restrict__ csr) {
    __shared__ unsigned ebuf_s[BK_CAP];      // 32 KB
    __shared__ int hist[NPB];
    __shared__ int sm[256];
    __shared__ int lcur[NPB];
    const int b = blockIdx.x;
    const int node0 = b * NPB;
    const int nn = N_NODES - node0;
    const int elo = bstart[b], ehi = bstart[b + 1];
    const int t = threadIdx.x;

    for (int i = t; i < NPB; i += blockDim.x) hist[i] = 0;
    __syncthreads();
    {
        const int base0 = elo & ~3;          // 16B-aligned start
        for (int e4 = base0 + t * 4; e4 < ehi; e4 += 4096) {
            vint4 q = *(const vint4*)&ebuf[e4];
            int qq[4] = {q.x, q.y, q.z, q.w};
#pragma unroll
            for (int r = 0; r < 4; ++r) {
                int e = e4 + r;
                if (e >= elo && e < ehi) {
                    unsigned pk = (unsigned)qq[r];
                    int idx = e - elo;
                    if (idx < BK_CAP) ebuf_s[idx] = pk;
                    atomicAdd(&hist[pk >> 17], 1);
                }
            }
        }
    }
    __syncthreads();
    int orig = 0;
    if (t < 256) { orig = (t < NPB) ? hist[t] : 0; sm[t] = orig; }
    __syncthreads();
    for (int off = 1; off < 256; off <<= 1) {
        int v = 0;
        if (t < 256 && t >= off) v = sm[t - off];
        __syncthreads();
        if (t < 256) sm[t] += v;
        __syncthreads();
    }
    if (t < NPB) {
        int ex = sm[t] - orig;
        lcur[t] = ex;
        if (t < nn) {
            int node = node0 + t;
            rowstart[node] = elo + ex;
            deg[node] = orig;
            float di = rsqrtf((float)(orig + 1));
            dinv[node] = di;
            zs1[node] = di * x[node];
        }
    }
    __syncthreads();
    for (int e = elo + t; e < ehi; e += blockDim.x) {
        int idx = e - elo;
        unsigned pk = (idx < BK_CAP) ? ebuf_s[idx] : ebuf[e];
        int pos = atomicAdd(&lcur[pk >> 17], 1);
        csr[elo + pos] = (int)(pk & 0x1FFFFu);
    }
}

// ---------------- layer 1: scalar gather -> sd = (s, dinv) ----------------

__global__ void k_gather1(const int* __restrict__ rowstart, const int* __restrict__ deg,
                          const int* __restrict__ csr, const float* __restrict__ dinv,
                          const float* __restrict__ zs1, float2* __restrict__ sd) {
    int v = blockIdx.x * NB + threadIdx.x;
    if (v < N_NODES) {
        int lo = rowstart[v], n = deg[v];
        float acc = zs1[v];
        int j = 0;
        for (; j + 4 <= n; j += 4) {
            int u0 = __builtin_nontemporal_load(&csr[lo + j]);
            int u1 = __builtin_nontemporal_load(&csr[lo + j + 1]);
            int u2 = __builtin_nontemporal_load(&csr[lo + j + 2]);
            int u3 = __builtin_nontemporal_load(&csr[lo + j + 3]);
            float a0 = zs1[u0], a1 = zs1[u1], a2 = zs1[u2], a3 = zs1[u3];
            acc += (a0 + a1) + (a2 + a3);
        }
        for (; j < n; ++j) acc += zs1[csr[lo + j]];
        float di = dinv[v];
        sd[v] = make_float2(di * acc, di);
    }
}

// ---------------- layer 2: LDS-staged rank-1 gather (SoA, packed-f32 consume) ----------------
// Block = 16 nodes (512 thr); block's edges contiguous in CSR. Window w+1 gathered
// into registers while window w is consumed from LDS. Staged window is SoA
// (s[] / d[]) so the consume runs two isomorphic f32 chains -> v_pk_* codegen.
__global__ void __launch_bounds__(G2_THREADS) k_gather2(
                          const int* __restrict__ rowstart, const int* __restrict__ deg,
                          const int* __restrict__ csr, const float2* __restrict__ sd,
                          const float* __restrict__ W1, const float* __restrict__ b1,
                          const float* __restrict__ g1, const float* __restrict__ bb1,
                          const float* __restrict__ m1, const float* __restrict__ v1,
                          const float* __restrict__ W2,
                          const float* __restrict__ b2, const float* __restrict__ g2,
                          const float* __restrict__ bb2, const float* __restrict__ m2,
                          const float* __restrict__ v2,
                          unsigned short* __restrict__ zs3a,
                          unsigned short* __restrict__ zs3b) {
    __shared__ float Ws[HID * HID];
    __shared__ __align__(16) float sde_s[G2_WCAP];
    __shared__ __align__(16) float sde_d[G2_WCAP];
    __shared__ float rowbuf[G2_NODES][HID + 1];
    __shared__ int sb[2];
    const int tid = threadIdx.x;
    for (int k = tid; k < HID * HID; k += G2_THREADS) Ws[k] = W2[k];

    const int r = tid >> 5, f = tid & 31;
    const int v = blockIdx.x * G2_NODES + r;
    const bool valid = v < N_NODES;

    if (tid == 0) {
        int first = blockIdx.x * G2_NODES;
        int last = min(first + G2_NODES - 1, N_NODES - 1);
        sb[0] = rowstart[first];
        sb[1] = rowstart[last] + deg[last];
    }

    const float sc1 = g1[f] * rsqrtf(v1[f] + BN_EPS);
    const float A = W1[f] * sc1;
    const float Bc = (b1[f] - m1[f]) * sc1 + bb1[f];

    float di = 0.0f, acc = 0.0f;
    int rs = 0, re = 0;
    if (valid) {
        rs = rowstart[v];
        re = rs + deg[v];
        float2 pv = sd[v];
        di = pv.y;
        acc = di * fmaxf(pv.x * A + Bc, 0.0f);   // self-loop term zs2[v]
    }
    __syncthreads();
    const int blo = sb[0], bhi = sb[1];

    // prologue: gather window 0 into registers
    float2 pre[G2_EPT];
    {
        int wn0 = min(G2_WCAP, bhi - blo);
#pragma unroll
        for (int k = 0; k < G2_EPT; ++k) {
            int i = k * G2_THREADS + tid;
            pre[k] = (i < wn0)
                ? sd[__builtin_nontemporal_load(&csr[blo + i])]
                : make_float2(0.0f, 0.0f);
        }
    }

    float acc0 = 0.0f, acc1 = 0.0f;
    for (int w = blo; w < bhi; w += G2_WCAP) {
        const int wn = min(G2_WCAP, bhi - w);
        // write staged regs -> LDS (SoA)
#pragma unroll
        for (int k = 0; k < G2_EPT; ++k) {
            int i = k * G2_THREADS + tid;
            if (i < wn) { sde_s[i] = pre[k].x; sde_d[i] = pre[k].y; }
        }
        // prefetch next window into regs (overlaps with consume below)
        const int wnext = w + G2_WCAP;
        if (wnext < bhi) {
            int wn2 = min(G2_WCAP, bhi - wnext);
#pragma unroll
            for (int k = 0; k < G2_EPT; ++k) {
                int i = k * G2_THREADS + tid;
                pre[k] = (i < wn2)
                    ? sd[__builtin_nontemporal_load(&csr[wnext + i])]
                    : make_float2(0.0f, 0.0f);
            }
        }
        __syncthreads();
        int jlo = max(rs, w) - w;
        int jhi = min(re, w + wn) - w;
        int j = jlo;
        for (; j < jhi && (j & 3); ++j)          // peel to 16B alignment
            acc += sde_d[j] * fmaxf(sde_s[j] * A + Bc, 0.0f);
        const float4* ss4 = (const float4*)sde_s;
        const float4* dd4 = (const float4*)sde_d;
        for (; j + 4 <= jhi; j += 4) {
            float4 s4 = ss4[j >> 2];
            float4 d4 = dd4[j >> 2];
            float t0 = fmaxf(s4.x * A + Bc, 0.0f);
            float t1 = fmaxf(s4.y * A + Bc, 0.0f);
            float t2 = fmaxf(s4.z * A + Bc, 0.0f);
            float t3 = fmaxf(s4.w * A + Bc, 0.0f);
            acc0 += d4.x * t0;
            acc1 += d4.y * t1;
            acc0 += d4.z * t2;
            acc1 += d4.w * t3;
        }
        for (; j < jhi; ++j)
            acc += sde_d[j] * fmaxf(sde_s[j] * A + Bc, 0.0f);
        __syncthreads();
    }
    acc = (acc + acc0) + acc1;
    acc *= di;                 // agg2[v,f]
    rowbuf[r][f] = acc;
    __syncthreads();
    if (valid) {
        float h = b2[f];
#pragma unroll
        for (int k = 0; k < HID; ++k) h += rowbuf[r][k] * Ws[k * HID + f];
        float sc2 = g2[f] * rsqrtf(v2[f] + BN_EPS);
        float z = fmaxf((h - m2[f]) * sc2 + bb2[f], 0.0f);
        unsigned short o = f2bf(di * z);
        if (f < 16) zs3a[v * 16 + f] = o;
        else        zs3b[v * 16 + (f - 16)] = o;
    }
}

// ---------------- layer 3: half-feature gather, 8 lanes/node, uint loads ----------------
// tabu: [N][8] uints (= [N][16] bf16). Lane f2 owns features {2f2, 2f2+1}.

__global__ void k_gather3h(const int* __restrict__ rowstart, const int* __restrict__ deg,
                           const int* __restrict__ csr, const float* __restrict__ dinv,
                           const unsigned* __restrict__ tabu,      // [N][8] uint
                           unsigned* __restrict__ agg3u, int halfuofs) {  // [N][16] uint
    int t = blockIdx.x * NB + threadIdx.x;
    int v = t >> 3, f2 = t & 7;
    if (v < N_NODES) {
        int lo = rowstart[v], n = deg[v];
        unsigned ws = tabu[v * 8 + f2];          // self-loop term
        float a0 = bf2f_lo(ws), a1 = bf2f_hi(ws);
        int j = 0;
        for (; j + 8 <= n; j += 8) {
            int u0 = __builtin_nontemporal_load(&csr[lo + j]);
            int u1 = __builtin_nontemporal_load(&csr[lo + j + 1]);
            int u2 = __builtin_nontemporal_load(&csr[lo + j + 2]);
            int u3 = __builtin_nontemporal_load(&csr[lo + j + 3]);
            int u4 = __builtin_nontemporal_load(&csr[lo + j + 4]);
            int u5 = __builtin_nontemporal_load(&csr[lo + j + 5]);
            int u6 = __builtin_nontemporal_load(&csr[lo + j + 6]);
            int u7 = __builtin_nontemporal_load(&csr[lo + j + 7]);
            unsigned w0 = tabu[u0 * 8 + f2];
            unsigned w1 = tabu[u1 * 8 + f2];
            unsigned w2 = tabu[u2 * 8 + f2];
            unsigned w3 = tabu[u3 * 8 + f2];
            unsigned w4 = tabu[u4 * 8 + f2];
            unsigned w5 = tabu[u5 * 8 + f2];
            unsigned w6 = tabu[u6 * 8 + f2];
            unsigned w7 = tabu[u7 * 8 + f2];
            a0 += ((bf2f_lo(w0) + bf2f_lo(w1)) + (bf2f_lo(w2) + bf2f_lo(w3)))
                + ((bf2f_lo(w4) + bf2f_lo(w5)) + (bf2f_lo(w6) + bf2f_lo(w7)));
            a1 += ((bf2f_hi(w0) + bf2f_hi(w1)) + (bf2f_hi(w2) + bf2f_hi(w3)))
                + ((bf2f_hi(w4) + bf2f_hi(w5)) + (bf2f_hi(w6) + bf2f_hi(w7)));
        }
        for (; j < n; ++j) {
            unsigned w = tabu[__builtin_nontemporal_load(&csr[lo + j]) * 8 + f2];
            a0 += bf2f_lo(w);
            a1 += bf2f_hi(w);
        }
        float di = dinv[v];
        unsigned o = (unsigned)f2bf(di * a0) | ((unsigned)f2bf(di * a1) << 16);
        __builtin_nontemporal_store(o, &agg3u[v * 16 + halfuofs + f2]);
    }
}

// ---------------- pool: block per graph, mean then matmul W3 ----------------

__global__ void k_pool(const unsigned short* __restrict__ agg3h,
                       const int* __restrict__ batch,
                       const float* __restrict__ W3, const float* __restrict__ b3,
                       float* __restrict__ out) {
    __shared__ float Ws[HID * HID];
    __shared__ float part[NB / HID][HID + 1];
    __shared__ float mrow[HID];
    int g = blockIdx.x;
    for (int k = threadIdx.x; k < HID * HID; k += NB) Ws[k] = W3[k];

    int lo = lbound(batch, N_NODES, g);
    int hi = lbound(batch, N_NODES, g + 1);

    int r = threadIdx.x >> 5, f = threadIdx.x & 31;
    float acc = 0.0f;
    for (int i = lo + r; i < hi; i += NB / HID)
        acc += bf2f(__builtin_nontemporal_load(&agg3h[i * HID + f]));
    part[r][f] = acc;
    __syncthreads();
    if (threadIdx.x < HID) {
        float srow = 0.0f;
#pragma unroll
        for (int k = 0; k < NB / HID; ++k) srow += part[k][threadIdx.x];
        float c = (float)(hi - lo);
        mrow[threadIdx.x] = (hi > lo) ? srow / c : 0.0f;
    }
    __syncthreads();
    if (threadIdx.x < HID) {
        int ff = threadIdx.x;
        float o = 0.0f;
        if (hi > lo) {
            o = b3[ff];
#pragma unroll
            for (int k = 0; k < HID; ++k) o += mrow[k] * Ws[k * HID + ff];
        }
        out[g * HID + ff] = o;
    }
}

// ---------------- launch ----------------

extern "C" void kernel_launch(void* const* d_in, const int* in_sizes, int n_in,
                              void* d_out, int out_size, void* d_ws, size_t ws_size,
                              hipStream_t stream) {
    const float* x     = (const float*)d_in[0];
    const int*   eidx  = (const int*)d_in[1];     // [2, E]: row0 = src, row1 = dst
    const int*   batch = (const int*)d_in[2];
    const float* W1    = (const float*)d_in[3];
    const float* b1    = (const float*)d_in[4];
    const float* bn1g  = (const float*)d_in[5];
    const float* bn1b  = (const float*)d_in[6];
    const float* bn1m  = (const float*)d_in[7];
    const float* bn1v  = (const float*)d_in[8];
    const float* W2    = (const float*)d_in[9];
    const float* b2    = (const float*)d_in[10];
    const float* bn2g  = (const float*)d_in[11];
    const float* bn2b  = (const float*)d_in[12];
    const float* bn2m  = (const float*)d_in[13];
    const float* bn2v  = (const float*)d_in[14];
    const float* W3    = (const float*)d_in[15];
    const float* b3    = (const float*)d_in[16];
    float* out = (float*)d_out;

    const int* src = eidx;
    const int* dst = eidx + N_EDGES;

    // workspace carving (256B aligned)
    char* ws = (char*)d_ws;
    size_t off = 0;
    auto carve = [&](size_t bytes) {
        void* p = ws + off;
        off += (bytes + 255) & ~size_t(255);
        return p;
    };
    int*    bhist    = (int*)carve(NBKT * 4);
    int*    bstart   = (int*)carve((NBKT + 1) * 4);
    int*    bcursor  = (int*)carve(NBKT * 4);
    int*    rowstart = (int*)carve(N_NODES * 4);
    int*    deg      = (int*)carve(N_NODES * 4);
    float*  dinv     = (float*)carve(N_NODES * 4);
    float*  zs1      = (float*)carve(N_NODES * 4);
    float2* sd       = (float2*)carve((size_t)N_NODES * 8);        // 0.8 MB (L2-resident)
    int*    csr      = (int*)carve((size_t)N_EDGES * 4);           // 12.8 MB
    // 12.8 MB region: ebuf dead after k_bucket; then zs3a(3.2) | zs3b(3.2) | agg3h(6.4)
    char*   region   = (char*)carve((size_t)N_EDGES * 4);
    unsigned*       ebuf  = (unsigned*)region;
    unsigned short* zs3a  = (unsigned short*)region;
    unsigned short* zs3b  = (unsigned short*)(region + (size_t)N_NODES * 16 * 2);
    unsigned short* agg3h = (unsigned short*)(region + (size_t)N_NODES * 32 * 2);
    unsigned*       agg3u = (unsigned*)agg3h;

    const int gN    = (N_NODES + NB - 1) / NB;                 // 391
    const int gG2   = (N_NODES + G2_NODES - 1) / G2_NODES;     // 6250
    const int gG3   = (N_NODES * 8 + NB - 1) / NB;             // 3125
    const int gPart = (N_EDGES + PART_TILE - 1) / PART_TILE;   // 391

    k_zero<<<1, NBKT, 0, stream>>>(bhist);
    k_hist<<<1024, NB, 0, stream>>>(dst, bhist);
    k_scan512<<<1, NBKT, 0, stream>>>(bhist, bstart, bcursor);
    k_partition<<<gPart, PART_THREADS, 0, stream>>>(src, dst, bcursor, ebuf);
    k_bucket<<<NBKT, 1024, 0, stream>>>(bstart, ebuf, x, rowstart, deg, dinv, zs1, csr);
    k_gather1<<<gN, NB, 0, stream>>>(rowstart, deg, csr, dinv, zs1, sd);
    k_gather2<<<gG2, G2_THREADS, 0, stream>>>(rowstart, deg, csr, sd,
                                      W1, b1, bn1g, bn1b, bn1m, bn1v,
                                      W2, b2, bn2g, bn2b, bn2m, bn2v, zs3a, zs3b);
    k_gather3h<<<gG3, NB, 0, stream>>>(rowstart, deg, csr, dinv,
                                       (const unsigned*)zs3a, agg3u, 0);
    k_gather3h<<<gG3, NB, 0, stream>>>(rowstart, deg, csr, dinv,
                                       (const unsigned*)zs3b, agg3u, 8);
    k_pool<<<N_GRAPHS, NB, 0, stream>>>(agg3h, batch, W3, b3, out);
}